// Round 5
// baseline (9314.803 us; speedup 1.0000x reference)
//
#include <hip/hip_runtime.h>
#include <stdint.h>

typedef __attribute__((ext_vector_type(8))) _Float16 half8;
typedef __attribute__((ext_vector_type(4))) float f32x4;

// ---------- ws element offsets (fp16 units) ----------
#define O_PW  0L           // [128 jg][4 kq][16 kb][768] fp16 = 6,291,456 (fragment-major)
#define O_X   6291456L     // [512 s][128 b][1024 k] fp16 = 67,108,864
#define O_HB  73400320L    // [2][128][1024] fp16 ping-pong = 262,144
#define O_CNT 73662464L    // 512 x u32 step counters (byte 147,324,928)

// LDS: W 98,304 + xch 24,576 + htr 3,072 = 125,952 B  (1 block/CU)
#define LDS_BYTES 125952

// ---------- prep: pack weights fragment-major fp16 (same as R4) ----------
__global__ void prep_w(const float* __restrict__ Wih, const float* __restrict__ Whh,
                       _Float16* __restrict__ pw)
{
    long i = (long)blockIdx.x * 256 + threadIdx.x;   // 6,291,456 total
    if (i >= 6291456L) return;
    int jg = (int)(i / 49152);
    int r  = (int)(i % 49152);
    int kq = r / 12288;  r %= 12288;
    int kb = r / 768;    r %= 768;
    int slot = r >> 3, e = r & 7;
    int wrow, kg;
    if (slot < 64) {                 // T0: z | r
        int c = slot & 15; kg = slot >> 4;
        wrow = (c < 8) ? (jg * 8 + c) : (1024 + jg * 8 + (c - 8));
    } else {                         // T1: n (row/row+8 dup at read)
        int idx = slot - 64; kg = idx >> 3;
        wrow = 2048 + jg * 8 + (idx & 7);
    }
    int klocal = (kq & 1) * 512 + kb * 32 + kg * 8 + e;
    const float* src = (kq >> 1) ? Whh : Wih;
    pw[i] = (_Float16)src[(long)wrow * 1024 + klocal];
}

// ---------- prep: x (B,S,I) f32 -> (S,B,I) fp16 (same as R4) ----------
__global__ void prep_x(const float* __restrict__ x, _Float16* __restrict__ xh)
{
    long t = (long)blockIdx.x * 256 + threadIdx.x;
    long base = t * 8;
    if (base >= 67108864L) return;
    long b = base >> 19;
    long rem = base & 524287L;
    long s = rem >> 10;
    long k = rem & 1023L;
    const float4* xp = (const float4*)(x + base);
    float4 v0 = xp[0], v1 = xp[1];
    half8 sv;
    sv[0] = (_Float16)v0.x; sv[1] = (_Float16)v0.y;
    sv[2] = (_Float16)v0.z; sv[3] = (_Float16)v0.w;
    sv[4] = (_Float16)v1.x; sv[5] = (_Float16)v1.y;
    sv[6] = (_Float16)v1.z; sv[7] = (_Float16)v1.w;
    *(half8*)(xh + ((s * 128 + b) << 10) + k) = sv;
}

// ---------- prep: h0 -> hb[0] via L3 (atomic write-through), hn tail, zero counters ----------
__global__ void prep_h(const float* __restrict__ h0, unsigned long long* __restrict__ hb64,
                       float* __restrict__ outTail, unsigned int* __restrict__ cnt)
{
    int i = blockIdx.x * 256 + threadIdx.x;          // 32768 threads x 4 f32
    float4 v = *(const float4*)(h0 + (long)i * 4);
    union { _Float16 h[4]; unsigned long long u; } p;
    p.h[0] = (_Float16)v.x; p.h[1] = (_Float16)v.y;
    p.h[2] = (_Float16)v.z; p.h[3] = (_Float16)v.w;
    __hip_atomic_store(&hb64[i], p.u, __ATOMIC_RELAXED, __HIP_MEMORY_SCOPE_AGENT);
    *(float4*)(outTail + (long)i * 4) = v;
    if (i < 512) __hip_atomic_store(&cnt[i], 0u, __ATOMIC_RELAXED, __HIP_MEMORY_SCOPE_AGENT);
}

// ---------- A-fragment load: normal (x, L2-cached) or L3-coherent (h) ----------
static __device__ __forceinline__ half8 loadA(const _Float16* p, bool via) {
    if (via) {
        unsigned long long* q = (unsigned long long*)p;
        unsigned long long u0 = __hip_atomic_load(q,     __ATOMIC_RELAXED, __HIP_MEMORY_SCOPE_AGENT);
        unsigned long long u1 = __hip_atomic_load(q + 1, __ATOMIC_RELAXED, __HIP_MEMORY_SCOPE_AGENT);
        union { unsigned long long u[2]; half8 h; } z;
        z.u[0] = u0; z.u[1] = u1;
        return z.h;
    }
    return *(const half8*)p;
}

// ---------- persistent GRU ----------
// grid 256 = 128 jg x 2 mg; 512 thr = 8 waves: mt2 = wave&1, kq = wave>>1 (0-1 x, 2-3 h).
// Weights LDS-resident (once). h crosses XCDs via relaxed agent atomics (no fences).
__global__ __launch_bounds__(512) void gru_persist(
    const _Float16* __restrict__ xh, const _Float16* __restrict__ pw,
    _Float16* __restrict__ hb, unsigned int* __restrict__ cnt,
    const float* __restrict__ bias, const float* __restrict__ h0,
    float* __restrict__ out)
{
    extern __shared__ char smem[];
    f32x4* xch = (f32x4*)(smem + 98304);
    float* htr = (float*)(smem + 122880);   // [64 b][12 stride] f32 transpose pad

    const int tid  = threadIdx.x;
    const int wave = tid >> 6, lane = tid & 63;
    const int mt2  = wave & 1, kq = wave >> 1;
    const int kh   = kq >> 1;                  // 0 = x half, 1 = h half
    const int ksrc = (kq & 1) * 512;
    const int row  = lane & 15, kg = lane >> 4;
    const int jg   = blockIdx.x >> 1, mg = blockIdx.x & 1;
    const int j0   = jg << 3, mgbase = mg << 6;
    const int t1x  = (lane & 7) | ((lane >> 4) << 3);

    // ---- stage weights ONCE: 98,304 B linear via global_load_lds ----
    {
        const char* src = (const char*)(pw + (long)jg * 49152);
        #pragma unroll
        for (int it = 0; it < 12; ++it) {
            int off = it * 8192 + tid * 16;
            __builtin_amdgcn_global_load_lds(
                (const __attribute__((address_space(1))) unsigned int*)(src + off),
                (__attribute__((address_space(3))) unsigned int*)(smem + off), 16, 0, 0);
        }
    }
    asm volatile("s_waitcnt vmcnt(0)" ::: "memory");
    __syncthreads();

    // ---- f32 master h in registers of epilogue lanes (kq0, row<8) ----
    float hreg[2][4];
    #pragma unroll
    for (int mi = 0; mi < 2; ++mi)
        #pragma unroll
        for (int i = 0; i < 4; ++i) {
            int b = mgbase + mt2 * 32 + mi * 16 + (kg << 2) + i;
            hreg[mi][i] = (kq == 0 && row < 8) ? h0[((long)b << 10) + j0 + (row & 7)] : 0.f;
        }

    const float bz = bias[j0 + (row & 7)];
    const float br = bias[1024 + j0 + (row & 7)];
    const float bn = bias[2048 + j0 + (row & 7)];

    const char* Bbase = smem + kq * 24576;
    unsigned long long* hb64base = (unsigned long long*)hb;
    #define MFMA(a,b,c) __builtin_amdgcn_mfma_f32_16x16x32_f16((a),(b),(c),0,0,0)

    for (int s = 0; s < 512; ++s) {
        // ---- h-waves: fence-free barrier wait (relaxed polls, no buffer_inv) ----
        if (kh && s > 0) {
            unsigned int v;
            do {
                v = __hip_atomic_load(&cnt[s - 1], __ATOMIC_RELAXED, __HIP_MEMORY_SCOPE_AGENT);
                if (v < 256u) __builtin_amdgcn_s_sleep(2);
            } while (v < 256u);
            asm volatile("" ::: "memory");
            __builtin_amdgcn_sched_barrier(0);
        }

        const _Float16* Asrc = kh ? (hb + ((long)(s & 1) << 17)) : (xh + ((long)s << 17));
        const _Float16* a0p = Asrc + (long)(mgbase + mt2 * 32 + row) * 1024 + ksrc + kg * 8;
        const _Float16* a1p = a0p + 16 * 1024;

        // depth-8 prefetch queue (static indexing only)
        half8 qa0[8], qa1[8];
        #pragma unroll
        for (int p = 0; p < 8; ++p) { qa0[p] = loadA(a0p + p * 32, kh);
                                      qa1[p] = loadA(a1p + p * 32, kh); }

        f32x4 acc00 = {0,0,0,0}, acc01 = {0,0,0,0};
        f32x4 acc10 = {0,0,0,0}, acc11 = {0,0,0,0};
        #pragma unroll
        for (int kb = 0; kb < 16; ++kb) {
            half8 fa0 = qa0[kb & 7], fa1 = qa1[kb & 7];
            half8 fb0 = *(const half8*)(Bbase + kb * 1536 + lane * 16);
            half8 fb1 = *(const half8*)(Bbase + kb * 1536 + 1024 + t1x * 16);
            acc00 = MFMA(fa0, fb0, acc00);
            acc01 = MFMA(fa1, fb0, acc01);
            acc10 = MFMA(fa0, fb1, acc10);
            acc11 = MFMA(fa1, fb1, acc11);
            if (kb < 8) { qa0[kb & 7] = loadA(a0p + (kb + 8) * 32, kh);
                          qa1[kb & 7] = loadA(a1p + (kb + 8) * 32, kh); }
        }

        // ---- exchange partials across K-quarters ----
        __syncthreads();
        if (kq) {
            int base = ((mt2 * 3 + (kq - 1)) * 4) * 64 + lane;
            xch[base]       = acc00;
            xch[base + 64]  = acc01;
            xch[base + 128] = acc10;
            xch[base + 192] = acc11;
        }
        __syncthreads();

        if (kq == 0) {
            #define XC(q,a) xch[((mt2 * 3 + (q)) * 4 + (a)) * 64 + lane]
            f32x4 t0a0 = acc00 + XC(0,0) + XC(1,0) + XC(2,0);   // z|r full
            f32x4 t0a1 = acc01 + XC(0,1) + XC(1,1) + XC(2,1);
            f32x4 nx0  = acc10 + XC(0,2);                       // gx_n
            f32x4 nx1  = acc11 + XC(0,3);
            f32x4 nh0  = XC(1,2) + XC(2,2);                     // gh_n
            f32x4 nh1  = XC(1,3) + XC(2,3);

            #pragma unroll
            for (int mi = 0; mi < 2; ++mi) {
                f32x4 t0 = mi ? t0a1 : t0a0;
                f32x4 nx = mi ? nx1 : nx0;
                f32x4 nh = mi ? nh1 : nh0;
                #pragma unroll
                for (int i = 0; i < 4; ++i) {
                    float vr = __shfl(t0[i], lane + 8);          // r-pre (col row+8)
                    if (row < 8) {
                        float z = 1.f / (1.f + __expf(-(t0[i] + bz)));
                        float r = 1.f / (1.f + __expf(-(vr + br)));
                        float inner = nx[i] + bn + nh[i] + r * (nh[i] + bn);
                        float e2 = __expf(2.f * inner);
                        float n = 1.f - 2.f / (e2 + 1.f);        // tanh
                        float hv = (1.f - z) * n + z * hreg[mi][i];
                        hreg[mi][i] = hv;
                        int bl = (mt2 << 5) + (mi << 4) + (kg << 2) + i;
                        htr[bl * 12 + (row & 7)] = hv;
                    }
                }
            }

            // ---- same-wave LDS transpose readback -> packed coherent h store + out ----
            int bl = (mt2 << 5) + (lane >> 1);       // batch-local 0..63
            int hq4 = lane & 1;                       // j-quad
            float4 hq = *(const float4*)&htr[bl * 12 + hq4 * 4];
            union { _Float16 h[4]; unsigned long long u; } pk;
            pk.h[0] = (_Float16)hq.x; pk.h[1] = (_Float16)hq.y;
            pk.h[2] = (_Float16)hq.z; pk.h[3] = (_Float16)hq.w;
            long b = mgbase + bl;
            __hip_atomic_store(hb64base + ((long)((s + 1) & 1) << 15) + b * 256 + jg * 2 + hq4,
                               pk.u, __ATOMIC_RELAXED, __HIP_MEMORY_SCOPE_AGENT);
            *(float4*)(out + (b << 19) + ((long)s << 10) + j0 + hq4 * 4) = hq;
            asm volatile("s_waitcnt vmcnt(0)" ::: "memory");   // h visible at L3
        }

        __syncthreads();
        if (tid == 0)
            __hip_atomic_fetch_add(&cnt[s], 1u, __ATOMIC_RELAXED, __HIP_MEMORY_SCOPE_AGENT);
    }
}

extern "C" void kernel_launch(void* const* d_in, const int* in_sizes, int n_in,
                              void* d_out, int out_size, void* d_ws, size_t ws_size,
                              hipStream_t stream)
{
    const float* x    = (const float*)d_in[0];
    const float* Wih  = (const float*)d_in[1];
    const float* Whh  = (const float*)d_in[2];
    const float* bias = (const float*)d_in[3];
    const float* h0   = (const float*)d_in[4];
    float* out = (float*)d_out;

    _Float16* ws16 = (_Float16*)d_ws;
    _Float16* pw = ws16 + O_PW;
    _Float16* xh = ws16 + O_X;
    _Float16* hb = ws16 + O_HB;
    unsigned int* cnt = (unsigned int*)(ws16 + O_CNT);

    (void)hipFuncSetAttribute((const void*)gru_persist,
                              hipFuncAttributeMaxDynamicSharedMemorySize, LDS_BYTES);

    prep_w<<<24576, 256, 0, stream>>>(Wih, Whh, pw);
    prep_x<<<32768, 256, 0, stream>>>(x, xh);
    prep_h<<<128, 256, 0, stream>>>(h0, (unsigned long long*)hb, out + 67108864L, cnt);

    gru_persist<<<256, 512, LDS_BYTES, stream>>>(xh, pw, hb, cnt, bias, h0, out);
}

// Round 6
// 8185.580 us; speedup vs baseline: 1.1380x; 1.1380x over previous
//
#include <hip/hip_runtime.h>
#include <stdint.h>

typedef __attribute__((ext_vector_type(8))) _Float16 half8;
typedef __attribute__((ext_vector_type(4))) float f32x4;

// ---------- ws element offsets (fp16 units) ----------
#define O_PW  0L           // [128 jg][4 kq][16 kb][768] fp16 = 6,291,456 (fragment-major)
#define O_X   6291456L     // [512 s][128 b][1024 k] fp16 = 67,108,864
#define O_HB  73400320L    // [2][128][1024] fp16 ping-pong = 262,144
#define O_FLG 73662464L    // 256 x u32 per-block step flags

// LDS: W 98,304 + xch 24,576 + htr 3,072 + sflag = 125,960 B (1 block/CU)
#define LDS_BYTES 125968

// ---------- prep: pack weights fragment-major fp16 (same as R4/R5) ----------
__global__ void prep_w(const float* __restrict__ Wih, const float* __restrict__ Whh,
                       _Float16* __restrict__ pw)
{
    long i = (long)blockIdx.x * 256 + threadIdx.x;   // 6,291,456 total
    if (i >= 6291456L) return;
    int jg = (int)(i / 49152);
    int r  = (int)(i % 49152);
    int kq = r / 12288;  r %= 12288;
    int kb = r / 768;    r %= 768;
    int slot = r >> 3, e = r & 7;
    int wrow, kg;
    if (slot < 64) {                 // T0: z | r
        int c = slot & 15; kg = slot >> 4;
        wrow = (c < 8) ? (jg * 8 + c) : (1024 + jg * 8 + (c - 8));
    } else {                         // T1: n (row/row+8 dup at read)
        int idx = slot - 64; kg = idx >> 3;
        wrow = 2048 + jg * 8 + (idx & 7);
    }
    int klocal = (kq & 1) * 512 + kb * 32 + kg * 8 + e;
    const float* src = (kq >> 1) ? Whh : Wih;
    pw[i] = (_Float16)src[(long)wrow * 1024 + klocal];
}

// ---------- prep: x (B,S,I) f32 -> (S,B,I) fp16 ----------
__global__ void prep_x(const float* __restrict__ x, _Float16* __restrict__ xh)
{
    long t = (long)blockIdx.x * 256 + threadIdx.x;
    long base = t * 8;
    if (base >= 67108864L) return;
    long b = base >> 19;
    long rem = base & 524287L;
    long s = rem >> 10;
    long k = rem & 1023L;
    const float4* xp = (const float4*)(x + base);
    float4 v0 = xp[0], v1 = xp[1];
    half8 sv;
    sv[0] = (_Float16)v0.x; sv[1] = (_Float16)v0.y;
    sv[2] = (_Float16)v0.z; sv[3] = (_Float16)v0.w;
    sv[4] = (_Float16)v1.x; sv[5] = (_Float16)v1.y;
    sv[6] = (_Float16)v1.z; sv[7] = (_Float16)v1.w;
    *(half8*)(xh + ((s * 128 + b) << 10) + k) = sv;
}

// ---------- prep: h0 -> hb[0] (write-through), hn tail, zero flags ----------
__global__ void prep_h(const float* __restrict__ h0, unsigned long long* __restrict__ hb64,
                       float* __restrict__ outTail, unsigned int* __restrict__ flg)
{
    int i = blockIdx.x * 256 + threadIdx.x;          // 32768 threads x 4 f32
    float4 v = *(const float4*)(h0 + (long)i * 4);
    union { _Float16 h[4]; unsigned long long u; } p;
    p.h[0] = (_Float16)v.x; p.h[1] = (_Float16)v.y;
    p.h[2] = (_Float16)v.z; p.h[3] = (_Float16)v.w;
    __hip_atomic_store(&hb64[i], p.u, __ATOMIC_RELAXED, __HIP_MEMORY_SCOPE_AGENT);
    *(float4*)(outTail + (long)i * 4) = v;
    if (i < 256) __hip_atomic_store(&flg[i], 0u, __ATOMIC_RELAXED, __HIP_MEMORY_SCOPE_AGENT);
}

// ---------- A-fragment load: normal (x, L2-cached) or L3-coherent (h) ----------
static __device__ __forceinline__ half8 loadA(const _Float16* p, bool via) {
    if (via) {
        unsigned long long* q = (unsigned long long*)p;
        unsigned long long u0 = __hip_atomic_load(q,     __ATOMIC_RELAXED, __HIP_MEMORY_SCOPE_AGENT);
        unsigned long long u1 = __hip_atomic_load(q + 1, __ATOMIC_RELAXED, __HIP_MEMORY_SCOPE_AGENT);
        union { unsigned long long u[2]; half8 h; } z;
        z.u[0] = u0; z.u[1] = u1;
        return z.h;
    }
    return *(const half8*)p;
}

// ---------- persistent GRU ----------
// grid 256 = 128 jg x 2 mg; 512 thr = 8 waves: mt2 = wave&1, kq = wave>>1 (0-1 x, 2-3 h).
// Weights LDS-resident. Barrier: per-block flag stores (no RMW) + 1 poller wave/block.
__global__ __launch_bounds__(512) void gru_persist(
    const _Float16* __restrict__ xh, const _Float16* __restrict__ pw,
    _Float16* __restrict__ hb, unsigned int* __restrict__ flg,
    const float* __restrict__ bias, const float* __restrict__ h0,
    float* __restrict__ out)
{
    extern __shared__ char smem[];
    f32x4* xch = (f32x4*)(smem + 98304);
    float* htr = (float*)(smem + 122880);            // [64 b][12 stride] f32
    volatile int* sflag = (volatile int*)(smem + 125952);

    const int tid  = threadIdx.x;
    const int wave = tid >> 6, lane = tid & 63;
    const int mt2  = wave & 1, kq = wave >> 1;
    const int kh   = kq >> 1;                  // 0 = x half, 1 = h half
    const int ksrc = (kq & 1) * 512;
    const int row  = lane & 15, kg = lane >> 4;
    const int jg   = blockIdx.x >> 1, mg = blockIdx.x & 1;
    const int j0   = jg << 3, mgbase = mg << 6;
    const int t1x  = (lane & 7) | ((lane >> 4) << 3);

    // ---- stage weights ONCE: 98,304 B linear via global_load_lds ----
    {
        const char* src = (const char*)(pw + (long)jg * 49152);
        #pragma unroll
        for (int it = 0; it < 12; ++it) {
            int off = it * 8192 + tid * 16;
            __builtin_amdgcn_global_load_lds(
                (const __attribute__((address_space(1))) unsigned int*)(src + off),
                (__attribute__((address_space(3))) unsigned int*)(smem + off), 16, 0, 0);
        }
    }
    if (tid == 0) *sflag = 0;
    asm volatile("s_waitcnt vmcnt(0)" ::: "memory");
    __syncthreads();

    // ---- f32 master h in registers of epilogue lanes (kq0, row<8) ----
    float hreg[2][4];
    #pragma unroll
    for (int mi = 0; mi < 2; ++mi)
        #pragma unroll
        for (int i = 0; i < 4; ++i) {
            int b = mgbase + mt2 * 32 + mi * 16 + (kg << 2) + i;
            hreg[mi][i] = (kq == 0 && row < 8) ? h0[((long)b << 10) + j0 + (row & 8 ? 0 : row & 7)] : 0.f;
        }
    // (row&8 lanes unused in epilogue; value irrelevant but avoid OOB: row<8 guard above)

    const float bz = bias[j0 + (row & 7)];
    const float br = bias[1024 + j0 + (row & 7)];
    const float bn = bias[2048 + j0 + (row & 7)];

    const char* Bbase = smem + kq * 24576;
    unsigned long long* hb64base = (unsigned long long*)hb;
    #define MFMA(a,b,c) __builtin_amdgcn_mfma_f32_16x16x32_f16((a),(b),(c),0,0,0)

    for (int s = 0; s < 512; ++s) {
        // ---- h-waves: contention-free barrier wait ----
        if (kh && s > 0) {
            if (wave == 4) {
                bool ready;
                do {
                    unsigned v0 = __hip_atomic_load(&flg[lane],       __ATOMIC_RELAXED, __HIP_MEMORY_SCOPE_AGENT);
                    unsigned v1 = __hip_atomic_load(&flg[64 + lane],  __ATOMIC_RELAXED, __HIP_MEMORY_SCOPE_AGENT);
                    unsigned v2 = __hip_atomic_load(&flg[128 + lane], __ATOMIC_RELAXED, __HIP_MEMORY_SCOPE_AGENT);
                    unsigned v3 = __hip_atomic_load(&flg[192 + lane], __ATOMIC_RELAXED, __HIP_MEMORY_SCOPE_AGENT);
                    unsigned mn = min(min(v0, v1), min(v2, v3));
                    ready = __all((int)(mn >= (unsigned)s));
                    if (!ready) __builtin_amdgcn_s_sleep(1);
                } while (!ready);
                if (lane == 0) *sflag = s;
            } else {
                while (*sflag < s) { __builtin_amdgcn_s_sleep(1); }
            }
            asm volatile("" ::: "memory");
            __builtin_amdgcn_sched_barrier(0);
        }

        const _Float16* Asrc = kh ? (hb + ((long)(s & 1) << 17)) : (xh + ((long)s << 17));
        const _Float16* a0p = Asrc + (long)(mgbase + mt2 * 32 + row) * 1024 + ksrc + kg * 8;
        const _Float16* a1p = a0p + 16 * 1024;

        // full-depth prefetch: all 32 fragment loads in flight, static indexing
        half8 qa0[16], qa1[16];
        #pragma unroll
        for (int p = 0; p < 16; ++p) { qa0[p] = loadA(a0p + p * 32, kh);
                                       qa1[p] = loadA(a1p + p * 32, kh); }

        f32x4 acc00 = {0,0,0,0}, acc01 = {0,0,0,0};
        f32x4 acc10 = {0,0,0,0}, acc11 = {0,0,0,0};
        #pragma unroll
        for (int kb = 0; kb < 16; ++kb) {
            half8 fa0 = qa0[kb], fa1 = qa1[kb];
            half8 fb0 = *(const half8*)(Bbase + kb * 1536 + lane * 16);
            half8 fb1 = *(const half8*)(Bbase + kb * 1536 + 1024 + t1x * 16);
            acc00 = MFMA(fa0, fb0, acc00);
            acc01 = MFMA(fa1, fb0, acc01);
            acc10 = MFMA(fa0, fb1, acc10);
            acc11 = MFMA(fa1, fb1, acc11);
        }

        // ---- exchange partials across K-quarters ----
        __syncthreads();
        if (kq) {
            int base = ((mt2 * 3 + (kq - 1)) * 4) * 64 + lane;
            xch[base]       = acc00;
            xch[base + 64]  = acc01;
            xch[base + 128] = acc10;
            xch[base + 192] = acc11;
        }
        __syncthreads();

        if (kq == 0) {
            #define XC(q,a) xch[((mt2 * 3 + (q)) * 4 + (a)) * 64 + lane]
            f32x4 t0a0 = acc00 + XC(0,0) + XC(1,0) + XC(2,0);   // z|r full
            f32x4 t0a1 = acc01 + XC(0,1) + XC(1,1) + XC(2,1);
            f32x4 nx0  = acc10 + XC(0,2);                       // gx_n
            f32x4 nx1  = acc11 + XC(0,3);
            f32x4 nh0  = XC(1,2) + XC(2,2);                     // gh_n
            f32x4 nh1  = XC(1,3) + XC(2,3);

            #pragma unroll
            for (int mi = 0; mi < 2; ++mi) {
                f32x4 t0 = mi ? t0a1 : t0a0;
                f32x4 nx = mi ? nx1 : nx0;
                f32x4 nh = mi ? nh1 : nh0;
                #pragma unroll
                for (int i = 0; i < 4; ++i) {
                    float vr = __shfl(t0[i], lane + 8);          // r-pre (col row+8)
                    if (row < 8) {
                        float z = 1.f / (1.f + __expf(-(t0[i] + bz)));
                        float r = 1.f / (1.f + __expf(-(vr + br)));
                        float inner = nx[i] + bn + nh[i] + r * (nh[i] + bn);
                        float e2 = __expf(2.f * inner);
                        float n = 1.f - 2.f / (e2 + 1.f);        // tanh
                        float hv = (1.f - z) * n + z * hreg[mi][i];
                        hreg[mi][i] = hv;
                        int bl = (mt2 << 5) + (mi << 4) + (kg << 2) + i;
                        htr[bl * 12 + (row & 7)] = hv;
                    }
                }
            }

            // ---- same-wave LDS transpose -> packed write-through h store + out ----
            int bl = (mt2 << 5) + (lane >> 1);       // batch-local 0..63
            int hq4 = lane & 1;                       // j-quad
            float4 hq = *(const float4*)&htr[bl * 12 + hq4 * 4];
            union { _Float16 h[4]; unsigned long long u; } pk;
            pk.h[0] = (_Float16)hq.x; pk.h[1] = (_Float16)hq.y;
            pk.h[2] = (_Float16)hq.z; pk.h[3] = (_Float16)hq.w;
            long b = mgbase + bl;
            __hip_atomic_store(hb64base + ((long)((s + 1) & 1) << 15) + b * 256 + jg * 2 + hq4,
                               pk.u, __ATOMIC_RELAXED, __HIP_MEMORY_SCOPE_AGENT);
            *(float4*)(out + (b << 19) + ((long)s << 10) + j0 + hq4 * 4) = hq;
            asm volatile("s_waitcnt vmcnt(0)" ::: "memory");   // h visible at L3
        }

        __syncthreads();
        // ---- release: per-block flag STORE (no RMW, no shared line contention) ----
        if (tid == 0)
            __hip_atomic_store(&flg[blockIdx.x], (unsigned)(s + 1),
                               __ATOMIC_RELAXED, __HIP_MEMORY_SCOPE_AGENT);
    }
}

extern "C" void kernel_launch(void* const* d_in, const int* in_sizes, int n_in,
                              void* d_out, int out_size, void* d_ws, size_t ws_size,
                              hipStream_t stream)
{
    const float* x    = (const float*)d_in[0];
    const float* Wih  = (const float*)d_in[1];
    const float* Whh  = (const float*)d_in[2];
    const float* bias = (const float*)d_in[3];
    const float* h0   = (const float*)d_in[4];
    float* out = (float*)d_out;

    _Float16* ws16 = (_Float16*)d_ws;
    _Float16* pw = ws16 + O_PW;
    _Float16* xh = ws16 + O_X;
    _Float16* hb = ws16 + O_HB;
    unsigned int* flg = (unsigned int*)(ws16 + O_FLG);

    (void)hipFuncSetAttribute((const void*)gru_persist,
                              hipFuncAttributeMaxDynamicSharedMemorySize, LDS_BYTES);

    prep_w<<<24576, 256, 0, stream>>>(Wih, Whh, pw);
    prep_x<<<32768, 256, 0, stream>>>(x, xh);
    prep_h<<<128, 256, 0, stream>>>(h0, (unsigned long long*)hb, out + 67108864L, flg);

    gru_persist<<<256, 512, LDS_BYTES, stream>>>(xh, pw, hb, flg, bias, h0, out);
}

// Round 7
// 7207.766 us; speedup vs baseline: 1.2923x; 1.1357x over previous
//
#include <hip/hip_runtime.h>
#include <stdint.h>

typedef __attribute__((ext_vector_type(8))) _Float16 half8;
typedef __attribute__((ext_vector_type(4))) float f32x4;

// ---------- ws element offsets (fp16 units) ----------
#define O_PW  0L           // [128 jg][4 kq][16 kb][768] fp16 = 6,291,456 (fragment-major)
#define O_X   6291456L     // [512 s][128 b][1024 k] fp16 = 67,108,864
#define O_HB  73400320L    // [2][128][1024] fp16 ping-pong = 262,144
#define O_FLG 73662464L    // 256 x u32 per-block step flags

// LDS: W 98,304 + xch 24,576 + htr 3,072 + sflag = 125,960 B (1 block/CU)
#define LDS_BYTES 125968

// ---------- prep: pack weights fragment-major fp16 (same as R4-R6) ----------
__global__ void prep_w(const float* __restrict__ Wih, const float* __restrict__ Whh,
                       _Float16* __restrict__ pw)
{
    long i = (long)blockIdx.x * 256 + threadIdx.x;   // 6,291,456 total
    if (i >= 6291456L) return;
    int jg = (int)(i / 49152);
    int r  = (int)(i % 49152);
    int kq = r / 12288;  r %= 12288;
    int kb = r / 768;    r %= 768;
    int slot = r >> 3, e = r & 7;
    int wrow, kg;
    if (slot < 64) {                 // T0: z | r
        int c = slot & 15; kg = slot >> 4;
        wrow = (c < 8) ? (jg * 8 + c) : (1024 + jg * 8 + (c - 8));
    } else {                         // T1: n (row/row+8 dup at read)
        int idx = slot - 64; kg = idx >> 3;
        wrow = 2048 + jg * 8 + (idx & 7);
    }
    int klocal = (kq & 1) * 512 + kb * 32 + kg * 8 + e;
    const float* src = (kq >> 1) ? Whh : Wih;
    pw[i] = (_Float16)src[(long)wrow * 1024 + klocal];
}

// ---------- prep: x (B,S,I) f32 -> (S,B,I) fp16 ----------
__global__ void prep_x(const float* __restrict__ x, _Float16* __restrict__ xh)
{
    long t = (long)blockIdx.x * 256 + threadIdx.x;
    long base = t * 8;
    if (base >= 67108864L) return;
    long b = base >> 19;
    long rem = base & 524287L;
    long s = rem >> 10;
    long k = rem & 1023L;
    const float4* xp = (const float4*)(x + base);
    float4 v0 = xp[0], v1 = xp[1];
    half8 sv;
    sv[0] = (_Float16)v0.x; sv[1] = (_Float16)v0.y;
    sv[2] = (_Float16)v0.z; sv[3] = (_Float16)v0.w;
    sv[4] = (_Float16)v1.x; sv[5] = (_Float16)v1.y;
    sv[6] = (_Float16)v1.z; sv[7] = (_Float16)v1.w;
    *(half8*)(xh + ((s * 128 + b) << 10) + k) = sv;
}

// ---------- prep: h0 -> hb[0] (write-through), hn tail, zero flags ----------
__global__ void prep_h(const float* __restrict__ h0, unsigned long long* __restrict__ hb64,
                       float* __restrict__ outTail, unsigned int* __restrict__ flg)
{
    int i = blockIdx.x * 256 + threadIdx.x;          // 32768 threads x 4 f32
    float4 v = *(const float4*)(h0 + (long)i * 4);
    union { _Float16 h[4]; unsigned long long u; } p;
    p.h[0] = (_Float16)v.x; p.h[1] = (_Float16)v.y;
    p.h[2] = (_Float16)v.z; p.h[3] = (_Float16)v.w;
    __hip_atomic_store(&hb64[i], p.u, __ATOMIC_RELAXED, __HIP_MEMORY_SCOPE_AGENT);
    *(float4*)(outTail + (long)i * 4) = v;
    if (i < 256) __hip_atomic_store(&flg[i], 0u, __ATOMIC_RELAXED, __HIP_MEMORY_SCOPE_AGENT);
}

// ---------- persistent GRU ----------
// grid 256 = 128 jg x 2 mg; 512 thr = 8 waves: mt2 = wave&1, kq = wave>>1 (0-1 x, 2-3 h).
// Weights LDS-resident. h: write-through atomic stores; NORMAL cached loads made safe
// by ONE agent-scope acquire (buffer_inv) per block per step, executed by the poller
// wave between barrier-detect and the LDS go-flag publish.
__global__ __launch_bounds__(512) void gru_persist(
    const _Float16* __restrict__ xh, const _Float16* __restrict__ pw,
    _Float16* __restrict__ hb, unsigned int* __restrict__ flg,
    const float* __restrict__ bias, const float* __restrict__ h0,
    float* __restrict__ out)
{
    extern __shared__ char smem[];
    f32x4* xch = (f32x4*)(smem + 98304);
    float* htr = (float*)(smem + 122880);            // [64 b][12 stride] f32
    volatile int* sflag = (volatile int*)(smem + 125952);

    const int tid  = threadIdx.x;
    const int wave = tid >> 6, lane = tid & 63;
    const int mt2  = wave & 1, kq = wave >> 1;
    const int kh   = kq >> 1;                  // 0 = x half, 1 = h half
    const int ksrc = (kq & 1) * 512;
    const int row  = lane & 15, kg = lane >> 4;
    const int jg   = blockIdx.x >> 1, mg = blockIdx.x & 1;
    const int j0   = jg << 3, mgbase = mg << 6;
    const int t1x  = (lane & 7) | ((lane >> 4) << 3);

    // ---- stage weights ONCE: 98,304 B linear via global_load_lds ----
    {
        const char* src = (const char*)(pw + (long)jg * 49152);
        #pragma unroll
        for (int it = 0; it < 12; ++it) {
            int off = it * 8192 + tid * 16;
            __builtin_amdgcn_global_load_lds(
                (const __attribute__((address_space(1))) unsigned int*)(src + off),
                (__attribute__((address_space(3))) unsigned int*)(smem + off), 16, 0, 0);
        }
    }
    if (tid == 0) *sflag = 0;
    asm volatile("s_waitcnt vmcnt(0)" ::: "memory");
    __syncthreads();

    // ---- f32 master h in registers of epilogue lanes (kq0, row<8) ----
    float hreg[2][4];
    #pragma unroll
    for (int mi = 0; mi < 2; ++mi)
        #pragma unroll
        for (int i = 0; i < 4; ++i) {
            int b = mgbase + mt2 * 32 + mi * 16 + (kg << 2) + i;
            hreg[mi][i] = (kq == 0 && row < 8) ? h0[((long)b << 10) + j0 + (row & 7)] : 0.f;
        }

    const float bz = bias[j0 + (row & 7)];
    const float br = bias[1024 + j0 + (row & 7)];
    const float bn = bias[2048 + j0 + (row & 7)];

    const char* Bbase = smem + kq * 24576;
    unsigned long long* hb64base = (unsigned long long*)hb;
    #define MFMA(a,b,c) __builtin_amdgcn_mfma_f32_16x16x32_f16((a),(b),(c),0,0,0)

    for (int s = 0; s < 512; ++s) {
        // ---- h-waves: barrier wait; poller acquires (one buffer_inv) then publishes ----
        if (kh && s > 0) {
            if (wave == 4) {
                bool ready;
                do {
                    unsigned v0 = __hip_atomic_load(&flg[lane],       __ATOMIC_RELAXED, __HIP_MEMORY_SCOPE_AGENT);
                    unsigned v1 = __hip_atomic_load(&flg[64 + lane],  __ATOMIC_RELAXED, __HIP_MEMORY_SCOPE_AGENT);
                    unsigned v2 = __hip_atomic_load(&flg[128 + lane], __ATOMIC_RELAXED, __HIP_MEMORY_SCOPE_AGENT);
                    unsigned v3 = __hip_atomic_load(&flg[192 + lane], __ATOMIC_RELAXED, __HIP_MEMORY_SCOPE_AGENT);
                    unsigned mn = min(min(v0, v1), min(v2, v3));
                    ready = __all((int)(mn >= (unsigned)s));
                    if (!ready) __builtin_amdgcn_s_sleep(1);
                } while (!ready);
                // one agent-scope ACQUIRE: invalidates L1 + this XCD's L2 so the
                // normal cached h loads below observe this step's L3 data.
                unsigned acq = __hip_atomic_load(&flg[0], __ATOMIC_ACQUIRE, __HIP_MEMORY_SCOPE_AGENT);
                if (lane == 0) *sflag = (int)(acq >= (unsigned)s ? s : s);  // data-dep publish
            } else {
                while (*sflag < s) { __builtin_amdgcn_s_sleep(1); }
            }
            asm volatile("" ::: "memory");
            __builtin_amdgcn_sched_barrier(0);
        }

        const _Float16* Asrc = kh ? (hb + ((long)(s & 1) << 17)) : (xh + ((long)s << 17));
        const _Float16* a0p = Asrc + (long)(mgbase + mt2 * 32 + row) * 1024 + ksrc + kg * 8;
        const _Float16* a1p = a0p + 16 * 1024;

        // full-depth prefetch: all 32 fragment loads in flight, normal cached loads
        half8 qa0[16], qa1[16];
        #pragma unroll
        for (int p = 0; p < 16; ++p) { qa0[p] = *(const half8*)(a0p + p * 32);
                                       qa1[p] = *(const half8*)(a1p + p * 32); }

        f32x4 acc00 = {0,0,0,0}, acc01 = {0,0,0,0};
        f32x4 acc10 = {0,0,0,0}, acc11 = {0,0,0,0};
        #pragma unroll
        for (int kb = 0; kb < 16; ++kb) {
            half8 fa0 = qa0[kb], fa1 = qa1[kb];
            half8 fb0 = *(const half8*)(Bbase + kb * 1536 + lane * 16);
            half8 fb1 = *(const half8*)(Bbase + kb * 1536 + 1024 + t1x * 16);
            acc00 = MFMA(fa0, fb0, acc00);
            acc01 = MFMA(fa1, fb0, acc01);
            acc10 = MFMA(fa0, fb1, acc10);
            acc11 = MFMA(fa1, fb1, acc11);
        }

        // ---- exchange partials across K-quarters ----
        __syncthreads();
        if (kq) {
            int base = ((mt2 * 3 + (kq - 1)) * 4) * 64 + lane;
            xch[base]       = acc00;
            xch[base + 64]  = acc01;
            xch[base + 128] = acc10;
            xch[base + 192] = acc11;
        }
        __syncthreads();

        if (kq == 0) {
            #define XC(q,a) xch[((mt2 * 3 + (q)) * 4 + (a)) * 64 + lane]
            f32x4 t0a0 = acc00 + XC(0,0) + XC(1,0) + XC(2,0);   // z|r full
            f32x4 t0a1 = acc01 + XC(0,1) + XC(1,1) + XC(2,1);
            f32x4 nx0  = acc10 + XC(0,2);                       // gx_n
            f32x4 nx1  = acc11 + XC(0,3);
            f32x4 nh0  = XC(1,2) + XC(2,2);                     // gh_n
            f32x4 nh1  = XC(1,3) + XC(2,3);

            #pragma unroll
            for (int mi = 0; mi < 2; ++mi) {
                f32x4 t0 = mi ? t0a1 : t0a0;
                f32x4 nx = mi ? nx1 : nx0;
                f32x4 nh = mi ? nh1 : nh0;
                #pragma unroll
                for (int i = 0; i < 4; ++i) {
                    float vr = __shfl(t0[i], lane + 8);          // r-pre (col row+8)
                    if (row < 8) {
                        float z = 1.f / (1.f + __expf(-(t0[i] + bz)));
                        float r = 1.f / (1.f + __expf(-(vr + br)));
                        float inner = nx[i] + bn + nh[i] + r * (nh[i] + bn);
                        float e2 = __expf(2.f * inner);
                        float n = 1.f - 2.f / (e2 + 1.f);        // tanh
                        float hv = (1.f - z) * n + z * hreg[mi][i];
                        hreg[mi][i] = hv;
                        int bl = (mt2 << 5) + (mi << 4) + (kg << 2) + i;
                        htr[bl * 12 + (row & 7)] = hv;
                    }
                }
            }

            // ---- same-wave LDS transpose -> packed write-through h store + out ----
            int bl = (mt2 << 5) + (lane >> 1);       // batch-local 0..63
            int hq4 = lane & 1;                       // j-quad
            float4 hq = *(const float4*)&htr[bl * 12 + hq4 * 4];
            union { _Float16 h[4]; unsigned long long u; } pk;
            pk.h[0] = (_Float16)hq.x; pk.h[1] = (_Float16)hq.y;
            pk.h[2] = (_Float16)hq.z; pk.h[3] = (_Float16)hq.w;
            long b = mgbase + bl;
            __hip_atomic_store(hb64base + ((long)((s + 1) & 1) << 15) + b * 256 + jg * 2 + hq4,
                               pk.u, __ATOMIC_RELAXED, __HIP_MEMORY_SCOPE_AGENT);
            *(float4*)(out + (b << 19) + ((long)s << 10) + j0 + hq4 * 4) = hq;
            asm volatile("s_waitcnt vmcnt(0)" ::: "memory");   // h visible at L3
        }

        __syncthreads();
        // ---- release: per-block flag STORE (no RMW) ----
        if (tid == 0)
            __hip_atomic_store(&flg[blockIdx.x], (unsigned)(s + 1),
                               __ATOMIC_RELAXED, __HIP_MEMORY_SCOPE_AGENT);
    }
}

extern "C" void kernel_launch(void* const* d_in, const int* in_sizes, int n_in,
                              void* d_out, int out_size, void* d_ws, size_t ws_size,
                              hipStream_t stream)
{
    const float* x    = (const float*)d_in[0];
    const float* Wih  = (const float*)d_in[1];
    const float* Whh  = (const float*)d_in[2];
    const float* bias = (const float*)d_in[3];
    const float* h0   = (const float*)d_in[4];
    float* out = (float*)d_out;

    _Float16* ws16 = (_Float16*)d_ws;
    _Float16* pw = ws16 + O_PW;
    _Float16* xh = ws16 + O_X;
    _Float16* hb = ws16 + O_HB;
    unsigned int* flg = (unsigned int*)(ws16 + O_FLG);

    (void)hipFuncSetAttribute((const void*)gru_persist,
                              hipFuncAttributeMaxDynamicSharedMemorySize, LDS_BYTES);

    prep_w<<<24576, 256, 0, stream>>>(Wih, Whh, pw);
    prep_x<<<32768, 256, 0, stream>>>(x, xh);
    prep_h<<<128, 256, 0, stream>>>(h0, (unsigned long long*)hb, out + 67108864L, flg);

    gru_persist<<<256, 512, LDS_BYTES, stream>>>(xh, pw, hb, flg, bias, h0, out);
}

// Round 11
// 5742.559 us; speedup vs baseline: 1.6221x; 1.2551x over previous
//
#include <hip/hip_runtime.h>
#include <stdint.h>

typedef __attribute__((ext_vector_type(8))) _Float16 half8;
typedef __attribute__((ext_vector_type(4))) float f32x4;
typedef __attribute__((ext_vector_type(4))) unsigned int u32x4;
typedef __attribute__((ext_vector_type(2))) unsigned int u32x2;

// =====================================================================
//  FAST PATH (ws >= 349 MB): f32 gx precompute (4 chunks of 128 steps)
//  + persistent batch-domain recurrence, sc1 (device-scope / L3) coherence.
// =====================================================================
// ws byte offsets
#define WB_PWIH 0L            // W_ih fp16 [3072][1024]                 6,291,456
#define WB_PWHH 6291456L      // W_hh frags [32 role][6 w][32 kb][64][8] 6,291,456
#define WB_XH   12582912L     // x fp16 [128 b][512 s][1024]          134,217,728
#define WB_HB   146800640L    // h [8 dom][2][16 b][1024] fp16 swz        524,288
#define WB_HF   147324928L    // f32 h chunk handoff [128][1024]          524,288
#define WB_FLG  147849216L    // flg u32[256]                               4,096
#define WB_GX   147853312L    // gx f32 [128 sl][128 b][3072]         201,326,592
#define WS_NEED 349179904L

#define G1_LDS 69632
#define P_LDS  86016          // forces 1 block/CU (2x84KB > 160KB)

// ---------------- prep: W_ih f32 -> fp16 (row-major) ----------------
__global__ void prep_wih(const float* __restrict__ Wih, _Float16* __restrict__ p)
{
    long i = (long)blockIdx.x * 256 + threadIdx.x;     // 3,145,728
    if (i < 3145728L) p[i] = (_Float16)Wih[i];
}

// ---------------- prep: W_hh -> persistent-VGPR fragment order ----------------
// p[role][w][kb][lane][e]; w=(g,pp): j = 32*role+16*pp+(lane&15); G=g*1024+j;
// k = kb*32 + (lane>>4)*8 + e
__global__ void prep_whh(const float* __restrict__ Whh, _Float16* __restrict__ p)
{
    long i = (long)blockIdx.x * 256 + threadIdx.x;     // 3,145,728
    if (i >= 3145728L) return;
    int role = (int)(i / 98304);
    int r2 = (int)(i % 98304);
    int w  = r2 / 16384;  int r3 = r2 % 16384;
    int kb = r3 / 512;    int r4 = r3 % 512;
    int lane = r4 >> 3, e = r4 & 7;
    int g = w >> 1, pp = w & 1;
    int j = 32 * role + 16 * pp + (lane & 15);
    int G = g * 1024 + j;
    int k = kb * 32 + (lane >> 4) * 8 + e;
    p[i] = (_Float16)Whh[(long)G * 1024 + k];
}

// ---------------- prep: x f32 -> fp16, same [B][S][I] layout ----------------
__global__ void prep_xh(const float* __restrict__ x, _Float16* __restrict__ xh)
{
    long base = ((long)blockIdx.x * 256 + threadIdx.x) * 8;
    if (base >= 67108864L) return;
    float4 v0 = *(const float4*)(x + base);
    float4 v1 = *(const float4*)(x + base + 4);
    half8 sv;
    sv[0]=(_Float16)v0.x; sv[1]=(_Float16)v0.y; sv[2]=(_Float16)v0.z; sv[3]=(_Float16)v0.w;
    sv[4]=(_Float16)v1.x; sv[5]=(_Float16)v1.y; sv[6]=(_Float16)v1.z; sv[7]=(_Float16)v1.w;
    *(half8*)(xh + base) = sv;
}

// ---------------- prep: h0 -> swizzled fp16 hb buf0, hn tail, zero flags ----------------
__global__ void prep_hz(const float* __restrict__ h0, _Float16* __restrict__ hb,
                        float* __restrict__ outTail, unsigned int* __restrict__ flg)
{
    int i = blockIdx.x * 256 + threadIdx.x;            // 16384
    int dom = i >> 11, b = (i >> 7) & 15, c = i & 127;
    const float4* src = (const float4*)(h0 + ((long)(dom * 16 + b) << 10) + c * 8);
    float4 v0 = src[0], v1 = src[1];
    half8 hv;
    hv[0]=(_Float16)v0.x; hv[1]=(_Float16)v0.y; hv[2]=(_Float16)v0.z; hv[3]=(_Float16)v0.w;
    hv[4]=(_Float16)v1.x; hv[5]=(_Float16)v1.y; hv[6]=(_Float16)v1.z; hv[7]=(_Float16)v1.w;
    *(half8*)(hb + ((long)(dom * 2 + 0) * 16 + b) * 1024 + ((c ^ (b & 7)) << 3)) = hv;
    float4* t = (float4*)(outTail + ((long)(dom * 16 + b) << 10) + c * 8);
    t[0] = v0; t[1] = v1;
    if (i < 256) flg[i] = 0u;
}

// ---------------- gx GEMM (per 128-step chunk): gx[sl][b][G] = x.W_ih^T + bias, f32 out ----------------
// 3072 blocks = 128 b x 24 tn; 512 thr; tile 128m(steps) x 128G; K=1024.
__global__ __launch_bounds__(512) void gx_gemm(
    const _Float16* __restrict__ xh, const _Float16* __restrict__ pwih,
    const float* __restrict__ bias, float* __restrict__ gx, int cbase)
{
    extern __shared__ char sm[];
    _Float16* As = (_Float16*)sm;            // [2][128][68]
    _Float16* Bs = (_Float16*)(sm + 34816);  // [2][128][68]

    const int tid = threadIdx.x, wave = tid >> 6, lane = tid & 63;
    const int wm = wave >> 2, wn = wave & 3;
    const int b = blockIdx.x & 127, tn = blockIdx.x >> 7;
    const int n0 = tn << 7;
    const int row = tid >> 2, ko = (tid & 3) << 3;

    const _Float16* xs   = xh + ((long)b * 512 + cbase + row) * 1024 + ko;
    const _Float16* bsrc = pwih + (long)(n0 + row) * 1024 + ko;

    f32x4 acc[4][2];
    #pragma unroll
    for (int t = 0; t < 4; ++t)
        #pragma unroll
        for (int u = 0; u < 2; ++u) acc[t][u] = (f32x4){0,0,0,0};

    half8 aq = *(const half8*)xs;
    half8 bq = *(const half8*)bsrc;

    #define MFMAH(a,bb,c) __builtin_amdgcn_mfma_f32_16x16x32_f16((a),(bb),(c),0,0,0)
    for (int ks = 0; ks < 32; ++ks) {
        _Float16* Ab = As + (ks & 1) * 8704;
        _Float16* Bb = Bs + (ks & 1) * 8704;
        *(half8*)(Ab + row * 68 + ko) = aq;
        *(half8*)(Bb + row * 68 + ko) = bq;
        __syncthreads();
        if (ks < 31) {
            aq = *(const half8*)(xs + (ks + 1) * 32);
            bq = *(const half8*)(bsrc + (ks + 1) * 32);
        }
        half8 af[4], bf[2];
        #pragma unroll
        for (int t = 0; t < 4; ++t)
            af[t] = *(const half8*)(Ab + (wm * 64 + t * 16 + (lane & 15)) * 68 + ((lane >> 4) << 3));
        #pragma unroll
        for (int u = 0; u < 2; ++u)
            bf[u] = *(const half8*)(Bb + (wn * 32 + u * 16 + (lane & 15)) * 68 + ((lane >> 4) << 3));
        #pragma unroll
        for (int t = 0; t < 4; ++t)
            #pragma unroll
            for (int u = 0; u < 2; ++u)
                acc[t][u] = MFMAH(af[t], bf[u], acc[t][u]);
        __syncthreads();
    }

    // epilogue: +bias, f32 transpose via LDS, f32 store
    float* xch = (float*)sm;                           // 128 x 136 f32 = 69,632 B
    #pragma unroll
    for (int u = 0; u < 2; ++u) {
        int Gl = wn * 32 + u * 16 + (lane & 15);
        float bv = bias[n0 + Gl];
        #pragma unroll
        for (int t = 0; t < 4; ++t)
            #pragma unroll
            for (int i = 0; i < 4; ++i) {
                int mr = wm * 64 + t * 16 + ((lane >> 4) << 2) + i;
                xch[mr * 136 + Gl] = acc[t][u][i] + bv;
            }
    }
    __syncthreads();
    {
        int r = tid >> 2, q = tid & 3;
        const float* sp = xch + r * 136 + q * 32;
        float* dp = gx + ((long)r * 128 + b) * 3072 + n0 + q * 32;
        #pragma unroll
        for (int t = 0; t < 8; ++t)
            *(float4*)(dp + t * 4) = *(const float4*)(sp + t * 4);
    }
}

// ---------------- sc1 = device scope (L3 coherence point) ----------------
static __device__ __forceinline__ unsigned flag_ld(const unsigned* p) {
    unsigned r;
    asm volatile("global_load_dword %0, %1, off sc1\ns_waitcnt vmcnt(0)"
                 : "=v"(r) : "v"(p) : "memory");
    return r;
}
static __device__ __forceinline__ void flag_st(unsigned* p, unsigned v) {
    asm volatile("global_store_dword %0, %1, off sc1" :: "v"(p), "v"(v) : "memory");
}
static __device__ __forceinline__ u32x4 ld16cc(const void* p) {
    u32x4 r;
    asm volatile("global_load_dwordx4 %0, %1, off sc1" : "=v"(r) : "v"(p));
    return r;
}
static __device__ __forceinline__ void st8cc(void* p, u32x2 v) {
    asm volatile("global_store_dwordx2 %0, %1, off sc1" :: "v"(p), "v"(v) : "memory");
}

// ---------------- persistent batch-domain recurrence (one 128-step chunk) ----------------
// 256 blocks x 512 thr, 84KB LDS -> 1 block/CU. dom = blockIdx>>5 (16 batches),
// role = blockIdx&31 (j-slice of 32). Waves 0-5: GEMM (W_hh in VGPRs);
// waves 6-7: poll + stage h/gx + epilogue.
__global__ __launch_bounds__(512) void gru_persist2(
    const float* __restrict__ gxc, const _Float16* __restrict__ pwh,
    _Float16* __restrict__ hb, float* __restrict__ hf,
    unsigned int* __restrict__ flg, const float* __restrict__ bias,
    const float* __restrict__ hsrc, float* __restrict__ out, int cbase)
{
    extern __shared__ char smem[];           // hs 32768 | gxs 6144 | xch 6528
    float* gxs  = (float*)(smem + 32768);
    float* xchf = (float*)(smem + 38912);

    const int tid = threadIdx.x, wave = tid >> 6, lane = tid & 63;
    const int dom = blockIdx.x >> 5, role = blockIdx.x & 31;
    const int b0g = dom << 4;
    unsigned int* myflg = flg + dom * 32;
    char* hb_d = (char*)(hb + (long)dom * 32768);      // dom stride 64KB

    // ---- persistent W_hh fragments (waves 0-5): 128 VGPR ----
    half8 bf[32];
    if (wave < 6) {
        const _Float16* src = pwh + (((long)role * 6 + wave) * 2048 + lane) * 8;
        #pragma unroll
        for (int kb = 0; kb < 32; ++kb)
            bf[kb] = *(const half8*)(src + (long)kb * 512);
    }

    // ---- epilogue state (waves 6,7): 8 batches each, 4 j per lane ----
    const int wl = wave - 6;
    const int ebi = ((wl & 1) << 3) + (lane & 7);
    const int eo  = lane >> 3;
    float hreg[4], bn4[4];
    if (wave >= 6) {
        #pragma unroll
        for (int e = 0; e < 4; ++e) {
            int j = role * 32 + eo * 4 + e;
            hreg[e] = hsrc[((long)(b0g + ebi) << 10) + j];
            bn4[e]  = bias[2048 + j];
        }
    }

    #define MFMAH2(a,bb,c) __builtin_amdgcn_mfma_f32_16x16x32_f16((a),(bb),(c),0,0,0)

    for (int s = cbase; s < cbase + 128; ++s) {
        // ---- stager waves: stage gx, poll domain flags, stage h(s) ----
        if (wave >= 6) {
            if (wave == 6) {     // gx slice (plain cached loads; no flag dependency)
                const char* gsrc = (const char*)(gxc + ((long)(s - cbase) * 128 + b0g) * 3072);
                #pragma unroll
                for (int t = 0; t < 6; ++t) {
                    int id = t * 64 + lane;
                    int run = id >> 3, sub = id & 7;
                    int bb = run / 3, gg = run % 3;
                    long off = (long)bb * 12288 + gg * 4096 + role * 128 + sub * 16;
                    u32x4 v = *(const u32x4*)(gsrc + off);
                    *(u32x4*)((char*)gxs + run * 128 + sub * 16) = v;
                }
            }
            if (s > 0 && lane < 32) {
                unsigned v; int guard = 0;
                do {
                    v = flag_ld(&myflg[lane]);
                    if (v < (unsigned)s) __builtin_amdgcn_s_sleep(1);
                } while (v < (unsigned)s && ++guard < (1 << 20));
            }
            // stage 16KB of h each: 16 x 16B per lane, single vmcnt drain
            const char* hsb = hb_d + (long)(s & 1) * 32768;
            const int base = (wl & 1) << 4;
            u32x4 q[16];
            #pragma unroll
            for (int t = 0; t < 16; ++t)
                q[t] = ld16cc(hsb + (long)((base + t) * 64 + lane) * 16);
            asm volatile("s_waitcnt vmcnt(0)" ::: "memory");
            __builtin_amdgcn_sched_barrier(0);
            #pragma unroll
            for (int t = 0; t < 16; ++t)
                *(u32x4*)(smem + ((base + t) * 64 + lane) * 16) = q[t];
        }
        __syncthreads();                       // S1: h(s), gx(s) in LDS

        // ---- GEMM waves: one 16x16 tile over K=1024 ----
        if (wave < 6) {
            f32x4 acc = {0,0,0,0};
            const int ab = lane & 15, kg = lane >> 4;
            #pragma unroll
            for (int kb = 0; kb < 32; ++kb) {
                int ck = ((kb << 2) + kg) ^ (ab & 7);
                half8 af = *(const half8*)(smem + ab * 2048 + ck * 16);
                acc = MFMAH2(af, bf[kb], acc);
            }
            #pragma unroll
            for (int i = 0; i < 4; ++i)
                xchf[(wave * 16 + ((lane >> 4) << 2) + i) * 17 + ab] = acc[i];
        }
        __syncthreads();                       // S2: partials in xch

        // ---- waves 6,7: gates, h update, stores ----
        if (wave >= 6) {
            float hq[4];
            #pragma unroll
            for (int e = 0; e < 4; ++e) {
                int jl = eo * 4 + e;
                int p = jl >> 4, col = jl & 15;
                float gz  = xchf[(p * 16 + ebi) * 17 + col]       + gxs[(ebi * 3 + 0) * 32 + jl];
                float gr  = xchf[((2 + p) * 16 + ebi) * 17 + col] + gxs[(ebi * 3 + 1) * 32 + jl];
                float gn  = xchf[((4 + p) * 16 + ebi) * 17 + col];
                float gxn = gxs[(ebi * 3 + 2) * 32 + jl];
                float z = 1.f / (1.f + __expf(-gz));
                float r = 1.f / (1.f + __expf(-gr));
                float inner = gxn + gn + r * (gn + bn4[e]);
                float e2 = __expf(2.f * inner);
                float n = 1.f - 2.f / (e2 + 1.f);              // tanh
                float hv = (1.f - z) * n + z * hreg[e];
                hreg[e] = hv;
                hq[e] = hv;
            }
            union { _Float16 h[4]; u32x2 u; } pk;
            #pragma unroll
            for (int e = 0; e < 4; ++e) pk.h[e] = (_Float16)hq[e];
            int c16 = role * 4 + (eo >> 1);
            char* hdst = hb_d + (long)(((s + 1) & 1) * 16 + ebi) * 2048
                       + ((c16 ^ (ebi & 7)) << 4) + (eo & 1) * 8;
            st8cc(hdst, pk.u);
            float* od = out + ((long)(b0g + ebi) << 19) + ((long)s << 10) + role * 32 + eo * 4;
            *(float4*)od = (float4){hq[0], hq[1], hq[2], hq[3]};
            if (s == cbase + 127) {            // f32 handoff for next chunk
                float* hd = hf + ((long)(b0g + ebi) << 10) + role * 32 + eo * 4;
                *(float4*)hd = (float4){hq[0], hq[1], hq[2], hq[3]};
            }
            asm volatile("s_waitcnt vmcnt(0)" ::: "memory");   // h ACKed at L3
        }
        __syncthreads();                       // S3: both stager waves drained
        if (wave == 7 && lane == 0)
            flag_st(&myflg[role], (unsigned)(s + 1));
    }
}

// =====================================================================
//  FALLBACK PATH (R7, proven 7.2 ms): used when ws_size < WS_NEED
// =====================================================================
#define FO_PW  0L
#define FO_X   6291456L
#define FO_HB  73400320L
#define FO_FLG 73662464L
#define F_LDS_BYTES 125968

__global__ void prep_wF(const float* __restrict__ Wih, const float* __restrict__ Whh,
                        _Float16* __restrict__ pw)
{
    long i = (long)blockIdx.x * 256 + threadIdx.x;
    if (i >= 6291456L) return;
    int jg = (int)(i / 49152);
    int r  = (int)(i % 49152);
    int kq = r / 12288;  r %= 12288;
    int kb = r / 768;    r %= 768;
    int slot = r >> 3, e = r & 7;
    int wrow, kg;
    if (slot < 64) { int c = slot & 15; kg = slot >> 4;
        wrow = (c < 8) ? (jg * 8 + c) : (1024 + jg * 8 + (c - 8)); }
    else { int idx = slot - 64; kg = idx >> 3; wrow = 2048 + jg * 8 + (idx & 7); }
    int klocal = (kq & 1) * 512 + kb * 32 + kg * 8 + e;
    const float* src = (kq >> 1) ? Whh : Wih;
    pw[i] = (_Float16)src[(long)wrow * 1024 + klocal];
}

__global__ void prep_xF(const float* __restrict__ x, _Float16* __restrict__ xh)
{
    long t = (long)blockIdx.x * 256 + threadIdx.x;
    long base = t * 8;
    if (base >= 67108864L) return;
    const float4* xp = (const float4*)(x + base);
    float4 v0 = xp[0], v1 = xp[1];
    long b = base >> 19, rem = base & 524287L, s = rem >> 10, k = rem & 1023L;
    half8 sv;
    sv[0]=(_Float16)v0.x; sv[1]=(_Float16)v0.y; sv[2]=(_Float16)v0.z; sv[3]=(_Float16)v0.w;
    sv[4]=(_Float16)v1.x; sv[5]=(_Float16)v1.y; sv[6]=(_Float16)v1.z; sv[7]=(_Float16)v1.w;
    *(half8*)(xh + ((s * 128 + b) << 10) + k) = sv;
}

__global__ void prep_hF(const float* __restrict__ h0, unsigned long long* __restrict__ hb64,
                        float* __restrict__ outTail, unsigned int* __restrict__ flg)
{
    int i = blockIdx.x * 256 + threadIdx.x;
    float4 v = *(const float4*)(h0 + (long)i * 4);
    union { _Float16 h[4]; unsigned long long u; } p;
    p.h[0]=(_Float16)v.x; p.h[1]=(_Float16)v.y; p.h[2]=(_Float16)v.z; p.h[3]=(_Float16)v.w;
    __hip_atomic_store(&hb64[i], p.u, __ATOMIC_RELAXED, __HIP_MEMORY_SCOPE_AGENT);
    *(float4*)(outTail + (long)i * 4) = v;
    if (i < 256) __hip_atomic_store(&flg[i], 0u, __ATOMIC_RELAXED, __HIP_MEMORY_SCOPE_AGENT);
}

__global__ __launch_bounds__(512) void gru_persistF(
    const _Float16* __restrict__ xh, const _Float16* __restrict__ pw,
    _Float16* __restrict__ hb, unsigned int* __restrict__ flg,
    const float* __restrict__ bias, const float* __restrict__ h0,
    float* __restrict__ out)
{
    extern __shared__ char smem[];
    f32x4* xch = (f32x4*)(smem + 98304);
    float* htr = (float*)(smem + 122880);
    volatile int* sflag = (volatile int*)(smem + 125952);

    const int tid = threadIdx.x, wave = tid >> 6, lane = tid & 63;
    const int mt2 = wave & 1, kq = wave >> 1;
    const int kh = kq >> 1, ksrc = (kq & 1) * 512;
    const int row = lane & 15, kg = lane >> 4;
    const int jg = blockIdx.x >> 1, mg = blockIdx.x & 1;
    const int j0 = jg << 3, mgbase = mg << 6;
    const int t1x = (lane & 7) | ((lane >> 4) << 3);

    {
        const char* src = (const char*)(pw + (long)jg * 49152);
        #pragma unroll
        for (int it = 0; it < 12; ++it) {
            int off = it * 8192 + tid * 16;
            __builtin_amdgcn_global_load_lds(
                (const __attribute__((address_space(1))) unsigned int*)(src + off),
                (__attribute__((address_space(3))) unsigned int*)(smem + off), 16, 0, 0);
        }
    }
    if (tid == 0) *sflag = 0;
    asm volatile("s_waitcnt vmcnt(0)" ::: "memory");
    __syncthreads();

    float hreg[2][4];
    #pragma unroll
    for (int mi = 0; mi < 2; ++mi)
        #pragma unroll
        for (int i = 0; i < 4; ++i) {
            int b = mgbase + mt2 * 32 + mi * 16 + (kg << 2) + i;
            hreg[mi][i] = (kq == 0 && row < 8) ? h0[((long)b << 10) + j0 + (row & 7)] : 0.f;
        }
    const float bz = bias[j0 + (row & 7)];
    const float br = bias[1024 + j0 + (row & 7)];
    const float bn = bias[2048 + j0 + (row & 7)];
    const char* Bbase = smem + kq * 24576;
    unsigned long long* hb64base = (unsigned long long*)hb;
    #define MFMAF(a,b,c) __builtin_amdgcn_mfma_f32_16x16x32_f16((a),(b),(c),0,0,0)

    for (int s = 0; s < 512; ++s) {
        if (kh && s > 0) {
            if (wave == 4) {
                bool ready;
                do {
                    unsigned v0 = __hip_atomic_load(&flg[lane],       __ATOMIC_RELAXED, __HIP_MEMORY_SCOPE_AGENT);
                    unsigned v1 = __hip_atomic_load(&flg[64 + lane],  __ATOMIC_RELAXED, __HIP_MEMORY_SCOPE_AGENT);
                    unsigned v2 = __hip_atomic_load(&flg[128 + lane], __ATOMIC_RELAXED, __HIP_MEMORY_SCOPE_AGENT);
                    unsigned v3 = __hip_atomic_load(&flg[192 + lane], __ATOMIC_RELAXED, __HIP_MEMORY_SCOPE_AGENT);
                    unsigned mn = min(min(v0, v1), min(v2, v3));
                    ready = __all((int)(mn >= (unsigned)s));
                    if (!ready) __builtin_amdgcn_s_sleep(1);
                } while (!ready);
                unsigned acq = __hip_atomic_load(&flg[0], __ATOMIC_ACQUIRE, __HIP_MEMORY_SCOPE_AGENT);
                if (lane == 0) *sflag = (int)(acq >= (unsigned)s ? s : s);
            } else {
                while (*sflag < s) { __builtin_amdgcn_s_sleep(1); }
            }
            asm volatile("" ::: "memory");
            __builtin_amdgcn_sched_barrier(0);
        }

        const _Float16* Asrc = kh ? (hb + ((long)(s & 1) << 17)) : (xh + ((long)s << 17));
        const _Float16* a0p = Asrc + (long)(mgbase + mt2 * 32 + row) * 1024 + ksrc + kg * 8;
        const _Float16* a1p = a0p + 16 * 1024;
        half8 qa0[16], qa1[16];
        #pragma unroll
        for (int p = 0; p < 16; ++p) { qa0[p] = *(const half8*)(a0p + p * 32);
                                       qa1[p] = *(const half8*)(a1p + p * 32); }
        f32x4 acc00 = {0,0,0,0}, acc01 = {0,0,0,0};
        f32x4 acc10 = {0,0,0,0}, acc11 = {0,0,0,0};
        #pragma unroll
        for (int kb = 0; kb < 16; ++kb) {
            half8 fb0 = *(const half8*)(Bbase + kb * 1536 + lane * 16);
            half8 fb1 = *(const half8*)(Bbase + kb * 1536 + 1024 + t1x * 16);
            acc00 = MFMAF(qa0[kb], fb0, acc00);
            acc01 = MFMAF(qa1[kb], fb0, acc01);
            acc10 = MFMAF(qa0[kb], fb1, acc10);
            acc11 = MFMAF(qa1[kb], fb1, acc11);
        }
        __syncthreads();
        if (kq) {
            int base = ((mt2 * 3 + (kq - 1)) * 4) * 64 + lane;
            xch[base] = acc00; xch[base + 64] = acc01;
            xch[base + 128] = acc10; xch[base + 192] = acc11;
        }
        __syncthreads();
        if (kq == 0) {
            #define XCF(q,a) xch[((mt2 * 3 + (q)) * 4 + (a)) * 64 + lane]
            f32x4 t0a0 = acc00 + XCF(0,0) + XCF(1,0) + XCF(2,0);
            f32x4 t0a1 = acc01 + XCF(0,1) + XCF(1,1) + XCF(2,1);
            f32x4 nx0 = acc10 + XCF(0,2);
            f32x4 nx1 = acc11 + XCF(0,3);
            f32x4 nh0 = XCF(1,2) + XCF(2,2);
            f32x4 nh1 = XCF(1,3) + XCF(2,3);
            #pragma unroll
            for (int mi = 0; mi < 2; ++mi) {
                f32x4 t0 = mi ? t0a1 : t0a0;
                f32x4 nx = mi ? nx1 : nx0;
                f32x4 nh = mi ? nh1 : nh0;
                #pragma unroll
                for (int i = 0; i < 4; ++i) {
                    float vr = __shfl(t0[i], lane + 8);
                    if (row < 8) {
                        float z = 1.f / (1.f + __expf(-(t0[i] + bz)));
                        float r = 1.f / (1.f + __expf(-(vr + br)));
                        float inner = nx[i] + bn + nh[i] + r * (nh[i] + bn);
                        float e2 = __expf(2.f * inner);
                        float n = 1.f - 2.f / (e2 + 1.f);
                        float hv = (1.f - z) * n + z * hreg[mi][i];
                        hreg[mi][i] = hv;
                        int bl = (mt2 << 5) + (mi << 4) + (kg << 2) + i;
                        htr[bl * 12 + (row & 7)] = hv;
                    }
                }
            }
            int bl = (mt2 << 5) + (lane >> 1);
            int hq4 = lane & 1;
            float4 hq = *(const float4*)&htr[bl * 12 + hq4 * 4];
            union { _Float16 h[4]; unsigned long long u; } pk;
            pk.h[0]=(_Float16)hq.x; pk.h[1]=(_Float16)hq.y;
            pk.h[2]=(_Float16)hq.z; pk.h[3]=(_Float16)hq.w;
            long b = mgbase + bl;
            __hip_atomic_store(hb64base + ((long)((s + 1) & 1) << 15) + b * 256 + jg * 2 + hq4,
                               pk.u, __ATOMIC_RELAXED, __HIP_MEMORY_SCOPE_AGENT);
            *(float4*)(out + (b << 19) + ((long)s << 10) + j0 + hq4 * 4) = hq;
            asm volatile("s_waitcnt vmcnt(0)" ::: "memory");
        }
        __syncthreads();
        if (tid == 0)
            __hip_atomic_store(&flg[blockIdx.x], (unsigned)(s + 1),
                               __ATOMIC_RELAXED, __HIP_MEMORY_SCOPE_AGENT);
    }
}

// =====================================================================
extern "C" void kernel_launch(void* const* d_in, const int* in_sizes, int n_in,
                              void* d_out, int out_size, void* d_ws, size_t ws_size,
                              hipStream_t stream)
{
    const float* x    = (const float*)d_in[0];
    const float* Wih  = (const float*)d_in[1];
    const float* Whh  = (const float*)d_in[2];
    const float* bias = (const float*)d_in[3];
    const float* h0   = (const float*)d_in[4];
    float* out = (float*)d_out;
    char* ws = (char*)d_ws;

    if (ws_size >= (size_t)WS_NEED) {
        _Float16* pwih = (_Float16*)(ws + WB_PWIH);
        _Float16* pwh  = (_Float16*)(ws + WB_PWHH);
        _Float16* xh   = (_Float16*)(ws + WB_XH);
        _Float16* hb   = (_Float16*)(ws + WB_HB);
        float*    hf   = (float*)(ws + WB_HF);
        unsigned int* flg = (unsigned int*)(ws + WB_FLG);
        float*    gxf  = (float*)(ws + WB_GX);

        (void)hipFuncSetAttribute((const void*)gx_gemm,
                                  hipFuncAttributeMaxDynamicSharedMemorySize, G1_LDS);
        (void)hipFuncSetAttribute((const void*)gru_persist2,
                                  hipFuncAttributeMaxDynamicSharedMemorySize, P_LDS);

        prep_wih<<<12288, 256, 0, stream>>>(Wih, pwih);
        prep_whh<<<12288, 256, 0, stream>>>(Whh, pwh);
        prep_xh<<<32768, 256, 0, stream>>>(x, xh);
        prep_hz<<<64, 256, 0, stream>>>(h0, hb, out + 67108864L, flg);

        for (int c = 0; c < 4; ++c) {
            gx_gemm<<<3072, 512, G1_LDS, stream>>>(xh, pwih, bias, gxf, c * 128);
            gru_persist2<<<256, 512, P_LDS, stream>>>(gxf, pwh, hb, hf, flg, bias,
                                                      (c == 0) ? h0 : hf, out, c * 128);
        }
    } else {
        _Float16* ws16 = (_Float16*)d_ws;
        _Float16* pw = ws16 + FO_PW;
        _Float16* xh = ws16 + FO_X;
        _Float16* hb = ws16 + FO_HB;
        unsigned int* flg = (unsigned int*)(ws16 + FO_FLG);

        (void)hipFuncSetAttribute((const void*)gru_persistF,
                                  hipFuncAttributeMaxDynamicSharedMemorySize, F_LDS_BYTES);

        prep_wF<<<24576, 256, 0, stream>>>(Wih, Whh, pw);
        prep_xF<<<32768, 256, 0, stream>>>(x, xh);
        prep_hF<<<128, 256, 0, stream>>>(h0, (unsigned long long*)hb, out + 67108864L, flg);
        gru_persistF<<<256, 512, F_LDS_BYTES, stream>>>(xh, pw, hb, flg, bias, h0, out);
    }
}

// Round 12
// 3948.077 us; speedup vs baseline: 2.3593x; 1.4545x over previous
//
#include <hip/hip_runtime.h>
#include <stdint.h>

typedef __attribute__((ext_vector_type(8))) _Float16 half8;
typedef __attribute__((ext_vector_type(4))) float f32x4;
typedef __attribute__((ext_vector_type(4))) unsigned int u32x4;
typedef __attribute__((ext_vector_type(2))) unsigned int u32x2;

// =====================================================================
//  FAST PATH (ws >= 349 MB): f32 gx precompute (4 chunks of 128 steps)
//  + persistent batch-domain recurrence, sc1 (device-scope / L3) coherence.
// =====================================================================
// ws byte offsets
#define WB_PWIH 0L            // W_ih fp16 [3072][1024]                 6,291,456
#define WB_PWHH 6291456L      // W_hh frags [32 role][6 w][32 kb][64][8] 6,291,456
#define WB_XH   12582912L     // x fp16 [128 b][512 s][1024]          134,217,728
#define WB_HB   146800640L    // h [8 dom][2][16 b][1024] fp16 swz        524,288
#define WB_HF   147324928L    // f32 h chunk handoff [128][1024]          524,288
#define WB_FLG  147849216L    // flg u32[256]                               4,096
#define WB_GX   147853312L    // gx f32 [128 sl][128 b][3072]         201,326,592
#define WS_NEED 349179904L

#define G1_LDS 69632          // main loop 32KB (A/B dbuf) | epilogue xch 69.6KB
#define P_LDS  86016          // forces 1 block/CU for persist

// ---------------- prep: W_ih f32 -> fp16 (row-major) ----------------
__global__ void prep_wih(const float* __restrict__ Wih, _Float16* __restrict__ p)
{
    long i = (long)blockIdx.x * 256 + threadIdx.x;     // 3,145,728
    if (i < 3145728L) p[i] = (_Float16)Wih[i];
}

// ---------------- prep: W_hh -> persistent-VGPR fragment order ----------------
__global__ void prep_whh(const float* __restrict__ Whh, _Float16* __restrict__ p)
{
    long i = (long)blockIdx.x * 256 + threadIdx.x;     // 3,145,728
    if (i >= 3145728L) return;
    int role = (int)(i / 98304);
    int r2 = (int)(i % 98304);
    int w  = r2 / 16384;  int r3 = r2 % 16384;
    int kb = r3 / 512;    int r4 = r3 % 512;
    int lane = r4 >> 3, e = r4 & 7;
    int g = w >> 1, pp = w & 1;
    int j = 32 * role + 16 * pp + (lane & 15);
    int G = g * 1024 + j;
    int k = kb * 32 + (lane >> 4) * 8 + e;
    p[i] = (_Float16)Whh[(long)G * 1024 + k];
}

// ---------------- prep: x f32 -> fp16, same [B][S][I] layout ----------------
__global__ void prep_xh(const float* __restrict__ x, _Float16* __restrict__ xh)
{
    long base = ((long)blockIdx.x * 256 + threadIdx.x) * 8;
    if (base >= 67108864L) return;
    float4 v0 = *(const float4*)(x + base);
    float4 v1 = *(const float4*)(x + base + 4);
    half8 sv;
    sv[0]=(_Float16)v0.x; sv[1]=(_Float16)v0.y; sv[2]=(_Float16)v0.z; sv[3]=(_Float16)v0.w;
    sv[4]=(_Float16)v1.x; sv[5]=(_Float16)v1.y; sv[6]=(_Float16)v1.z; sv[7]=(_Float16)v1.w;
    *(half8*)(xh + base) = sv;
}

// ---------------- prep: h0 -> swizzled fp16 hb buf0, hn tail, zero flags ----------------
__global__ void prep_hz(const float* __restrict__ h0, _Float16* __restrict__ hb,
                        float* __restrict__ outTail, unsigned int* __restrict__ flg)
{
    int i = blockIdx.x * 256 + threadIdx.x;            // 16384
    int dom = i >> 11, b = (i >> 7) & 15, c = i & 127;
    const float4* src = (const float4*)(h0 + ((long)(dom * 16 + b) << 10) + c * 8);
    float4 v0 = src[0], v1 = src[1];
    half8 hv;
    hv[0]=(_Float16)v0.x; hv[1]=(_Float16)v0.y; hv[2]=(_Float16)v0.z; hv[3]=(_Float16)v0.w;
    hv[4]=(_Float16)v1.x; hv[5]=(_Float16)v1.y; hv[6]=(_Float16)v1.z; hv[7]=(_Float16)v1.w;
    *(half8*)(hb + ((long)(dom * 2 + 0) * 16 + b) * 1024 + ((c ^ (b & 7)) << 3)) = hv;
    float4* t = (float4*)(outTail + ((long)(dom * 16 + b) << 10) + c * 8);
    t[0] = v0; t[1] = v1;
    if (i < 256) flg[i] = 0u;
}

// ---------------- gx GEMM (m97-style): gx[sl][b][G] = x.W_ih^T + bias, f32 out ----------------
// Per chunk: 3072 blocks = 128 b x 24 tn; 256 thr = 4 waves (2x2); tile 128sl x 128G;
// BK=32, 32 K-steps; global_load_lds staging (linear LDS dest, source chunk-XOR swizzle).
__global__ __launch_bounds__(256) void gx_gemm(
    const _Float16* __restrict__ xh, const _Float16* __restrict__ pwih,
    const float* __restrict__ bias, float* __restrict__ gx, int cbase)
{
    extern __shared__ char sm[];                 // A dbuf [2][8192] | B dbuf [2][8192]
    char* As = sm;
    char* Bs = sm + 16384;

    const int tid = threadIdx.x, wave = tid >> 6, lane = tid & 63;
    const int wm = wave >> 1, wn = wave & 1;     // 2x2 waves, 64x64 each
    const int b = blockIdx.x & 127, tn = blockIdx.x >> 7;
    const int n0 = tn << 7;

    const char* xA = (const char*)(xh + ((long)b * 512 + cbase) * 1024);
    const char* xB = (const char*)(pwih + (long)n0 * 1024);

    // staging ids (2 issues x 256 thr): id -> row=id>>2, c=id&3; source chunk c^(row&3)
    int srow[2], soff[2];
    #pragma unroll
    for (int is = 0; is < 2; ++is) {
        int id = is * 256 + tid;
        srow[is] = id >> 2;
        soff[is] = ((id & 3) ^ (srow[is] & 3)) << 4;
    }

    #define GLDS(g, l) __builtin_amdgcn_global_load_lds( \
        (const __attribute__((address_space(1))) unsigned int*)(g), \
        (__attribute__((address_space(3))) unsigned int*)(l), 16, 0, 0)
    #define ISSUE(ks, bi) { \
        _Pragma("unroll") \
        for (int is = 0; is < 2; ++is) { \
            int id = is * 256 + tid; \
            GLDS(xA + (long)srow[is] * 2048 + (ks) * 64 + soff[is], As + (bi) * 8192 + id * 16); \
            GLDS(xB + (long)srow[is] * 2048 + (ks) * 64 + soff[is], Bs + (bi) * 8192 + id * 16); \
        } }

    f32x4 acc[4][4];
    #pragma unroll
    for (int fm = 0; fm < 4; ++fm)
        #pragma unroll
        for (int fn = 0; fn < 4; ++fn) acc[fm][fn] = (f32x4){0,0,0,0};

    const int r15 = lane & 15, kg = lane >> 4;
    const int sw = ((kg ^ (lane & 3)) << 4);     // read-side chunk XOR (row&3 == lane&3)

    ISSUE(0, 0);
    __syncthreads();

    #define MFMAH(a,bb,c) __builtin_amdgcn_mfma_f32_16x16x32_f16((a),(bb),(c),0,0,0)
    for (int ks = 0; ks < 32; ++ks) {
        const int bi = ks & 1;
        if (ks < 31) ISSUE(ks + 1, bi ^ 1);
        const char* Ab = As + bi * 8192;
        const char* Bb = Bs + bi * 8192;
        half8 af[4], bf[4];
        #pragma unroll
        for (int fm = 0; fm < 4; ++fm)
            af[fm] = *(const half8*)(Ab + (wm * 64 + fm * 16 + r15) * 64 + sw);
        #pragma unroll
        for (int fn = 0; fn < 4; ++fn)
            bf[fn] = *(const half8*)(Bb + (wn * 64 + fn * 16 + r15) * 64 + sw);
        #pragma unroll
        for (int fm = 0; fm < 4; ++fm)
            #pragma unroll
            for (int fn = 0; fn < 4; ++fn)
                acc[fm][fn] = MFMAH(af[fm], bf[fn], acc[fm][fn]);
        __syncthreads();                          // drains vmcnt+lgkmcnt (compiler)
    }

    // epilogue: +bias, f32 transpose via LDS, contiguous-G f32 store
    float* xch = (float*)sm;                     // [128 m][136] f32 = 69,632 B
    #pragma unroll
    for (int fn = 0; fn < 4; ++fn) {
        int ncol = wn * 64 + fn * 16 + r15;
        float bv = bias[n0 + ncol];
        #pragma unroll
        for (int fm = 0; fm < 4; ++fm)
            #pragma unroll
            for (int i = 0; i < 4; ++i) {
                int mr = wm * 64 + fm * 16 + (kg << 2) + i;
                xch[mr * 136 + ncol] = acc[fm][fn][i] + bv;
            }
    }
    __syncthreads();
    {
        int r = tid >> 1, q = tid & 1;           // r = sl row, q = half of G-tile
        const float* sp = xch + r * 136 + q * 64;
        float* dp = gx + ((long)r * 128 + b) * 3072 + n0 + q * 64;
        #pragma unroll
        for (int t = 0; t < 16; ++t)
            *(float4*)(dp + t * 4) = *(const float4*)(sp + t * 4);
    }
}

// ---------------- sc1 = device scope (L3 coherence point) ----------------
static __device__ __forceinline__ unsigned flag_ld(const unsigned* p) {
    unsigned r;
    asm volatile("global_load_dword %0, %1, off sc1\ns_waitcnt vmcnt(0)"
                 : "=v"(r) : "v"(p) : "memory");
    return r;
}
static __device__ __forceinline__ void flag_st(unsigned* p, unsigned v) {
    asm volatile("global_store_dword %0, %1, off sc1" :: "v"(p), "v"(v) : "memory");
}
static __device__ __forceinline__ u32x4 ld16cc(const void* p) {
    u32x4 r;
    asm volatile("global_load_dwordx4 %0, %1, off sc1" : "=v"(r) : "v"(p));
    return r;
}
static __device__ __forceinline__ void st8cc(void* p, u32x2 v) {
    asm volatile("global_store_dwordx2 %0, %1, off sc1" :: "v"(p), "v"(v) : "memory");
}

// ---------------- persistent batch-domain recurrence (one 128-step chunk) ----------------
// 256 blocks x 512 thr, 84KB LDS -> 1 block/CU. dom = blockIdx>>5 (16 batches),
// role = blockIdx&31 (j-slice of 32). Waves 0-5: GEMM (W_hh in VGPRs);
// waves 6-7: poll + stage h/gx + epilogue.  [unchanged from R11 — proven]
__global__ __launch_bounds__(512) void gru_persist2(
    const float* __restrict__ gxc, const _Float16* __restrict__ pwh,
    _Float16* __restrict__ hb, float* __restrict__ hf,
    unsigned int* __restrict__ flg, const float* __restrict__ bias,
    const float* __restrict__ hsrc, float* __restrict__ out, int cbase)
{
    extern __shared__ char smem[];           // hs 32768 | gxs 6144 | xch 6528
    float* gxs  = (float*)(smem + 32768);
    float* xchf = (float*)(smem + 38912);

    const int tid = threadIdx.x, wave = tid >> 6, lane = tid & 63;
    const int dom = blockIdx.x >> 5, role = blockIdx.x & 31;
    const int b0g = dom << 4;
    unsigned int* myflg = flg + dom * 32;
    char* hb_d = (char*)(hb + (long)dom * 32768);      // dom stride 64KB

    // ---- persistent W_hh fragments (waves 0-5): 128 VGPR ----
    half8 bf[32];
    if (wave < 6) {
        const _Float16* src = pwh + (((long)role * 6 + wave) * 2048 + lane) * 8;
        #pragma unroll
        for (int kb = 0; kb < 32; ++kb)
            bf[kb] = *(const half8*)(src + (long)kb * 512);
    }

    // ---- epilogue state (waves 6,7): 8 batches each, 4 j per lane ----
    const int wl = wave - 6;
    const int ebi = ((wl & 1) << 3) + (lane & 7);
    const int eo  = lane >> 3;
    float hreg[4], bn4[4];
    if (wave >= 6) {
        #pragma unroll
        for (int e = 0; e < 4; ++e) {
            int j = role * 32 + eo * 4 + e;
            hreg[e] = hsrc[((long)(b0g + ebi) << 10) + j];
            bn4[e]  = bias[2048 + j];
        }
    }

    #define MFMAH2(a,bb,c) __builtin_amdgcn_mfma_f32_16x16x32_f16((a),(bb),(c),0,0,0)

    for (int s = cbase; s < cbase + 128; ++s) {
        // ---- stager waves: stage gx, poll domain flags, stage h(s) ----
        if (wave >= 6) {
            if (wave == 6) {     // gx slice (plain cached loads; no flag dependency)
                const char* gsrc = (const char*)(gxc + ((long)(s - cbase) * 128 + b0g) * 3072);
                #pragma unroll
                for (int t = 0; t < 6; ++t) {
                    int id = t * 64 + lane;
                    int run = id >> 3, sub = id & 7;
                    int bb = run / 3, gg = run % 3;
                    long off = (long)bb * 12288 + gg * 4096 + role * 128 + sub * 16;
                    u32x4 v = *(const u32x4*)(gsrc + off);
                    *(u32x4*)((char*)gxs + run * 128 + sub * 16) = v;
                }
            }
            if (s > 0 && lane < 32) {
                unsigned v; int guard = 0;
                do {
                    v = flag_ld(&myflg[lane]);
                    if (v < (unsigned)s) __builtin_amdgcn_s_sleep(1);
                } while (v < (unsigned)s && ++guard < (1 << 20));
            }
            // stage 16KB of h each: 16 x 16B per lane, single vmcnt drain
            const char* hsb = hb_d + (long)(s & 1) * 32768;
            const int base = (wl & 1) << 4;
            u32x4 q[16];
            #pragma unroll
            for (int t = 0; t < 16; ++t)
                q[t] = ld16cc(hsb + (long)((base + t) * 64 + lane) * 16);
            asm volatile("s_waitcnt vmcnt(0)" ::: "memory");
            __builtin_amdgcn_sched_barrier(0);
            #pragma unroll
            for (int t = 0; t < 16; ++t)
                *(u32x4*)(smem + ((base + t) * 64 + lane) * 16) = q[t];
        }
        __syncthreads();                       // S1: h(s), gx(s) in LDS

        // ---- GEMM waves: one 16x16 tile over K=1024 ----
        if (wave < 6) {
            f32x4 acc = {0,0,0,0};
            const int ab = lane & 15, kg = lane >> 4;
            #pragma unroll
            for (int kb = 0; kb < 32; ++kb) {
                int ck = ((kb << 2) + kg) ^ (ab & 7);
                half8 af = *(const half8*)(smem + ab * 2048 + ck * 16);
                acc = MFMAH2(af, bf[kb], acc);
            }
            #pragma unroll
            for (int i = 0; i < 4; ++i)
                xchf[(wave * 16 + ((lane >> 4) << 2) + i) * 17 + ab] = acc[i];
        }
        __syncthreads();                       // S2: partials in xch

        // ---- waves 6,7: gates, h update, stores ----
        if (wave >= 6) {
            float hq[4];
            #pragma unroll
            for (int e = 0; e < 4; ++e) {
                int jl = eo * 4 + e;
                int p = jl >> 4, col = jl & 15;
                float gz  = xchf[(p * 16 + ebi) * 17 + col]       + gxs[(ebi * 3 + 0) * 32 + jl];
                float gr  = xchf[((2 + p) * 16 + ebi) * 17 + col] + gxs[(ebi * 3 + 1) * 32 + jl];
                float gn  = xchf[((4 + p) * 16 + ebi) * 17 + col];
                float gxn = gxs[(ebi * 3 + 2) * 32 + jl];
                float z = 1.f / (1.f + __expf(-gz));
                float r = 1.f / (1.f + __expf(-gr));
                float inner = gxn + gn + r * (gn + bn4[e]);
                float e2 = __expf(2.f * inner);
                float n = 1.f - 2.f / (e2 + 1.f);              // tanh
                float hv = (1.f - z) * n + z * hreg[e];
                hreg[e] = hv;
                hq[e] = hv;
            }
            union { _Float16 h[4]; u32x2 u; } pk;
            #pragma unroll
            for (int e = 0; e < 4; ++e) pk.h[e] = (_Float16)hq[e];
            int c16 = role * 4 + (eo >> 1);
            char* hdst = hb_d + (long)(((s + 1) & 1) * 16 + ebi) * 2048
                       + ((c16 ^ (ebi & 7)) << 4) + (eo & 1) * 8;
            st8cc(hdst, pk.u);
            float* od = out + ((long)(b0g + ebi) << 19) + ((long)s << 10) + role * 32 + eo * 4;
            *(float4*)od = (float4){hq[0], hq[1], hq[2], hq[3]};
            if (s == cbase + 127) {            // f32 handoff for next chunk
                float* hd = hf + ((long)(b0g + ebi) << 10) + role * 32 + eo * 4;
                *(float4*)hd = (float4){hq[0], hq[1], hq[2], hq[3]};
            }
            asm volatile("s_waitcnt vmcnt(0)" ::: "memory");   // h ACKed at L3
        }
        __syncthreads();                       // S3: both stager waves drained
        if (wave == 7 && lane == 0)
            flag_st(&myflg[role], (unsigned)(s + 1));
    }
}

// =====================================================================
//  FALLBACK PATH (R7, proven 7.2 ms): used when ws_size < WS_NEED
// =====================================================================
#define FO_PW  0L
#define FO_X   6291456L
#define FO_HB  73400320L
#define FO_FLG 73662464L
#define F_LDS_BYTES 125968

__global__ void prep_wF(const float* __restrict__ Wih, const float* __restrict__ Whh,
                        _Float16* __restrict__ pw)
{
    long i = (long)blockIdx.x * 256 + threadIdx.x;
    if (i >= 6291456L) return;
    int jg = (int)(i / 49152);
    int r  = (int)(i % 49152);
    int kq = r / 12288;  r %= 12288;
    int kb = r / 768;    r %= 768;
    int slot = r >> 3, e = r & 7;
    int wrow, kg;
    if (slot < 64) { int c = slot & 15; kg = slot >> 4;
        wrow = (c < 8) ? (jg * 8 + c) : (1024 + jg * 8 + (c - 8)); }
    else { int idx = slot - 64; kg = idx >> 3; wrow = 2048 + jg * 8 + (idx & 7); }
    int klocal = (kq & 1) * 512 + kb * 32 + kg * 8 + e;
    const float* src = (kq >> 1) ? Whh : Wih;
    pw[i] = (_Float16)src[(long)wrow * 1024 + klocal];
}

__global__ void prep_xF(const float* __restrict__ x, _Float16* __restrict__ xh)
{
    long t = (long)blockIdx.x * 256 + threadIdx.x;
    long base = t * 8;
    if (base >= 67108864L) return;
    const float4* xp = (const float4*)(x + base);
    float4 v0 = xp[0], v1 = xp[1];
    long b = base >> 19, rem = base & 524287L, s = rem >> 10, k = rem & 1023L;
    half8 sv;
    sv[0]=(_Float16)v0.x; sv[1]=(_Float16)v0.y; sv[2]=(_Float16)v0.z; sv[3]=(_Float16)v0.w;
    sv[4]=(_Float16)v1.x; sv[5]=(_Float16)v1.y; sv[6]=(_Float16)v1.z; sv[7]=(_Float16)v1.w;
    *(half8*)(xh + ((s * 128 + b) << 10) + k) = sv;
}

__global__ void prep_hF(const float* __restrict__ h0, unsigned long long* __restrict__ hb64,
                        float* __restrict__ outTail, unsigned int* __restrict__ flg)
{
    int i = blockIdx.x * 256 + threadIdx.x;
    float4 v = *(const float4*)(h0 + (long)i * 4);
    union { _Float16 h[4]; unsigned long long u; } p;
    p.h[0]=(_Float16)v.x; p.h[1]=(_Float16)v.y; p.h[2]=(_Float16)v.z; p.h[3]=(_Float16)v.w;
    __hip_atomic_store(&hb64[i], p.u, __ATOMIC_RELAXED, __HIP_MEMORY_SCOPE_AGENT);
    *(float4*)(outTail + (long)i * 4) = v;
    if (i < 256) __hip_atomic_store(&flg[i], 0u, __ATOMIC_RELAXED, __HIP_MEMORY_SCOPE_AGENT);
}

__global__ __launch_bounds__(512) void gru_persistF(
    const _Float16* __restrict__ xh, const _Float16* __restrict__ pw,
    _Float16* __restrict__ hb, unsigned int* __restrict__ flg,
    const float* __restrict__ bias, const float* __restrict__ h0,
    float* __restrict__ out)
{
    extern __shared__ char smem[];
    f32x4* xch = (f32x4*)(smem + 98304);
    float* htr = (float*)(smem + 122880);
    volatile int* sflag = (volatile int*)(smem + 125952);

    const int tid = threadIdx.x, wave = tid >> 6, lane = tid & 63;
    const int mt2 = wave & 1, kq = wave >> 1;
    const int kh = kq >> 1, ksrc = (kq & 1) * 512;
    const int row = lane & 15, kg = lane >> 4;
    const int jg = blockIdx.x >> 1, mg = blockIdx.x & 1;
    const int j0 = jg << 3, mgbase = mg << 6;
    const int t1x = (lane & 7) | ((lane >> 4) << 3);

    {
        const char* src = (const char*)(pw + (long)jg * 49152);
        #pragma unroll
        for (int it = 0; it < 12; ++it) {
            int off = it * 8192 + tid * 16;
            __builtin_amdgcn_global_load_lds(
                (const __attribute__((address_space(1))) unsigned int*)(src + off),
                (__attribute__((address_space(3))) unsigned int*)(smem + off), 16, 0, 0);
        }
    }
    if (tid == 0) *sflag = 0;
    asm volatile("s_waitcnt vmcnt(0)" ::: "memory");
    __syncthreads();

    float hreg[2][4];
    #pragma unroll
    for (int mi = 0; mi < 2; ++mi)
        #pragma unroll
        for (int i = 0; i < 4; ++i) {
            int b = mgbase + mt2 * 32 + mi * 16 + (kg << 2) + i;
            hreg[mi][i] = (kq == 0 && row < 8) ? h0[((long)b << 10) + j0 + (row & 7)] : 0.f;
        }
    const float bz = bias[j0 + (row & 7)];
    const float br = bias[1024 + j0 + (row & 7)];
    const float bn = bias[2048 + j0 + (row & 7)];
    const char* Bbase = smem + kq * 24576;
    unsigned long long* hb64base = (unsigned long long*)hb;
    #define MFMAF(a,b,c) __builtin_amdgcn_mfma_f32_16x16x32_f16((a),(b),(c),0,0,0)

    for (int s = 0; s < 512; ++s) {
        if (kh && s > 0) {
            if (wave == 4) {
                bool ready;
                do {
                    unsigned v0 = __hip_atomic_load(&flg[lane],       __ATOMIC_RELAXED, __HIP_MEMORY_SCOPE_AGENT);
                    unsigned v1 = __hip_atomic_load(&flg[64 + lane],  __ATOMIC_RELAXED, __HIP_MEMORY_SCOPE_AGENT);
                    unsigned v2 = __hip_atomic_load(&flg[128 + lane], __ATOMIC_RELAXED, __HIP_MEMORY_SCOPE_AGENT);
                    unsigned v3 = __hip_atomic_load(&flg[192 + lane], __ATOMIC_RELAXED, __HIP_MEMORY_SCOPE_AGENT);
                    unsigned mn = min(min(v0, v1), min(v2, v3));
                    ready = __all((int)(mn >= (unsigned)s));
                    if (!ready) __builtin_amdgcn_s_sleep(1);
                } while (!ready);
                unsigned acq = __hip_atomic_load(&flg[0], __ATOMIC_ACQUIRE, __HIP_MEMORY_SCOPE_AGENT);
                if (lane == 0) *sflag = (int)(acq >= (unsigned)s ? s : s);
            } else {
                while (*sflag < s) { __builtin_amdgcn_s_sleep(1); }
            }
            asm volatile("" ::: "memory");
            __builtin_amdgcn_sched_barrier(0);
        }

        const _Float16* Asrc = kh ? (hb + ((long)(s & 1) << 17)) : (xh + ((long)s << 17));
        const _Float16* a0p = Asrc + (long)(mgbase + mt2 * 32 + row) * 1024 + ksrc + kg * 8;
        const _Float16* a1p = a0p + 16 * 1024;
        half8 qa0[16], qa1[16];
        #pragma unroll
        for (int p = 0; p < 16; ++p) { qa0[p] = *(const half8*)(a0p + p * 32);
                                       qa1[p] = *(const half8*)(a1p + p * 32); }
        f32x4 acc00 = {0,0,0,0}, acc01 = {0,0,0,0};
        f32x4 acc10 = {0,0,0,0}, acc11 = {0,0,0,0};
        #pragma unroll
        for (int kb = 0; kb < 16; ++kb) {
            half8 fb0 = *(const half8*)(Bbase + kb * 1536 + lane * 16);
            half8 fb1 = *(const half8*)(Bbase + kb * 1536 + 1024 + t1x * 16);
            acc00 = MFMAF(qa0[kb], fb0, acc00);
            acc01 = MFMAF(qa1[kb], fb0, acc01);
            acc10 = MFMAF(qa0[kb], fb1, acc10);
            acc11 = MFMAF(qa1[kb], fb1, acc11);
        }
        __syncthreads();
        if (kq) {
            int base = ((mt2 * 3 + (kq - 1)) * 4) * 64 + lane;
            xch[base] = acc00; xch[base + 64] = acc01;
            xch[base + 128] = acc10; xch[base + 192] = acc11;
        }
        __syncthreads();
        if (kq == 0) {
            #define XCF(q,a) xch[((mt2 * 3 + (q)) * 4 + (a)) * 64 + lane]
            f32x4 t0a0 = acc00 + XCF(0,0) + XCF(1,0) + XCF(2,0);
            f32x4 t0a1 = acc01 + XCF(0,1) + XCF(1,1) + XCF(2,1);
            f32x4 nx0 = acc10 + XCF(0,2);
            f32x4 nx1 = acc11 + XCF(0,3);
            f32x4 nh0 = XCF(1,2) + XCF(2,2);
            f32x4 nh1 = XCF(1,3) + XCF(2,3);
            #pragma unroll
            for (int mi = 0; mi < 2; ++mi) {
                f32x4 t0 = mi ? t0a1 : t0a0;
                f32x4 nx = mi ? nx1 : nx0;
                f32x4 nh = mi ? nh1 : nh0;
                #pragma unroll
                for (int i = 0; i < 4; ++i) {
                    float vr = __shfl(t0[i], lane + 8);
                    if (row < 8) {
                        float z = 1.f / (1.f + __expf(-(t0[i] + bz)));
                        float r = 1.f / (1.f + __expf(-(vr + br)));
                        float inner = nx[i] + bn + nh[i] + r * (nh[i] + bn);
                        float e2 = __expf(2.f * inner);
                        float n = 1.f - 2.f / (e2 + 1.f);
                        float hv = (1.f - z) * n + z * hreg[mi][i];
                        hreg[mi][i] = hv;
                        int bl = (mt2 << 5) + (mi << 4) + (kg << 2) + i;
                        htr[bl * 12 + (row & 7)] = hv;
                    }
                }
            }
            int bl = (mt2 << 5) + (lane >> 1);
            int hq4 = lane & 1;
            float4 hq = *(const float4*)&htr[bl * 12 + hq4 * 4];
            union { _Float16 h[4]; unsigned long long u; } pk;
            pk.h[0]=(_Float16)hq.x; pk.h[1]=(_Float16)hq.y;
            pk.h[2]=(_Float16)hq.z; pk.h[3]=(_Float16)hq.w;
            long b = mgbase + bl;
            __hip_atomic_store(hb64base + ((long)((s + 1) & 1) << 15) + b * 256 + jg * 2 + hq4,
                               pk.u, __ATOMIC_RELAXED, __HIP_MEMORY_SCOPE_AGENT);
            *(float4*)(out + (b << 19) + ((long)s << 10) + j0 + hq4 * 4) = hq;
            asm volatile("s_waitcnt vmcnt(0)" ::: "memory");
        }
        __syncthreads();
        if (tid == 0)
            __hip_atomic_store(&flg[blockIdx.x], (unsigned)(s + 1),
                               __ATOMIC_RELAXED, __HIP_MEMORY_SCOPE_AGENT);
    }
}

// =====================================================================
extern "C" void kernel_launch(void* const* d_in, const int* in_sizes, int n_in,
                              void* d_out, int out_size, void* d_ws, size_t ws_size,
                              hipStream_t stream)
{
    const float* x    = (const float*)d_in[0];
    const float* Wih  = (const float*)d_in[1];
    const float* Whh  = (const float*)d_in[2];
    const float* bias = (const float*)d_in[3];
    const float* h0   = (const float*)d_in[4];
    float* out = (float*)d_out;
    char* ws = (char*)d_ws;

    if (ws_size >= (size_t)WS_NEED) {
        _Float16* pwih = (_Float16*)(ws + WB_PWIH);
        _Float16* pwh  = (_Float16*)(ws + WB_PWHH);
        _Float16* xh   = (_Float16*)(ws + WB_XH);
        _Float16* hb   = (_Float16*)(ws + WB_HB);
        float*    hf   = (float*)(ws + WB_HF);
        unsigned int* flg = (unsigned int*)(ws + WB_FLG);
        float*    gxf  = (float*)(ws + WB_GX);

        (void)hipFuncSetAttribute((const void*)gx_gemm,
                                  hipFuncAttributeMaxDynamicSharedMemorySize, G1_LDS);
        (void)hipFuncSetAttribute((const void*)gru_persist2,
                                  hipFuncAttributeMaxDynamicSharedMemorySize, P_LDS);

        prep_wih<<<12288, 256, 0, stream>>>(Wih, pwih);
        prep_whh<<<12288, 256, 0, stream>>>(Whh, pwh);
        prep_xh<<<32768, 256, 0, stream>>>(x, xh);
        prep_hz<<<64, 256, 0, stream>>>(h0, hb, out + 67108864L, flg);

        for (int c = 0; c < 4; ++c) {
            gx_gemm<<<3072, 256, G1_LDS, stream>>>(xh, pwih, bias, gxf, c * 128);
            gru_persist2<<<256, 512, P_LDS, stream>>>(gxf, pwh, hb, hf, flg, bias,
                                                      (c == 0) ? h0 : hf, out, c * 128);
        }
    } else {
        _Float16* ws16 = (_Float16*)d_ws;
        _Float16* pw = ws16 + FO_PW;
        _Float16* xh = ws16 + FO_X;
        _Float16* hb = ws16 + FO_HB;
        unsigned int* flg = (unsigned int*)(ws16 + FO_FLG);

        (void)hipFuncSetAttribute((const void*)gru_persistF,
                                  hipFuncAttributeMaxDynamicSharedMemorySize, F_LDS_BYTES);

        prep_wF<<<24576, 256, 0, stream>>>(Wih, Whh, pw);
        prep_xF<<<32768, 256, 0, stream>>>(x, xh);
        prep_hF<<<128, 256, 0, stream>>>(h0, (unsigned long long*)hb, out + 67108864L, flg);
        gru_persistF<<<256, 512, F_LDS_BYTES, stream>>>(xh, pw, hb, flg, bias, h0, out);
    }
}